// Round 1
// 772.449 us; speedup vs baseline: 1.2175x; 1.2175x over previous
//
#include <hip/hip_runtime.h>
#include <hip/hip_bf16.h>

#define NN 50000
#define EE 640000
#define NEG 0.2f
#define CAP 128          // per-segment cache; degree ~ Poisson(12.8), P(k>128) ~ 0

#define BSH 9                          // 512 dsts per bucket
#define NBKT 98                        // ceil(NN/512)
#define FCAP 7168                      // LDS record stage in bucket_final
#define CHUNKA 8192
#define PA_B 79                        // ceil(EE/CHUNKA)

struct Ptr8 { const int* p[8]; };
struct MArgs { const float* w[8]; const float* al[8]; const float* ar[8]; };

struct SegArg {
    const int* starts;
    const int* counts;
    const unsigned short* srt;
    const float* adst;
    const float* asrc;
    const unsigned short* feats;
    const float* pw;
    int pwi;
    int hasLoop;
};

typedef __attribute__((ext_vector_type(8))) short short8;
typedef __attribute__((ext_vector_type(8))) unsigned short ushort8;
typedef __attribute__((ext_vector_type(4))) float floatx4;

__device__ __forceinline__ unsigned short f2bf(float x) {
    unsigned b = __float_as_uint(x);
    b = b + 0x7fffu + ((b >> 16) & 1u);   // RNE
    return (unsigned short)(b >> 16);
}

// ---------------- transpose embedding weights ----------------
__global__ void transpose_emb(const float* __restrict__ wev, const float* __restrict__ wec,
                              float* __restrict__ out)
{
    int i = blockIdx.x * 256 + threadIdx.x;
    if (i < 8192) { out[i] = wev[(i & 127) * 64 + (i >> 7)]; return; }
    if (i < 16384) { int j = i - 8192; out[i] = wec[(j & 127) * 64 + (j >> 7)]; }
}

// ---------------- M[p] = W_p^T @ [attL | attR]  (128x8 per projection) ----------------
__global__ void make_M(MArgs a, float* __restrict__ Mbuf)
{
    int b = blockIdx.x;
    const float* W  = a.w[b];
    const float* AL = a.al[b];
    const float* AR = a.ar[b];
    for (int e = threadIdx.x; e < 1024; e += 256) {
        int k = e >> 3, h = e & 7;
        const float* att = (h < 4) ? AL : AR;
        int hh = h & 3;
        float s = 0.f;
        for (int c = 0; c < 128; c++) s += W[c * 128 + k] * att[c * 4 + hh];
        Mbuf[b * 1024 + e] = s;
    }
}

// ---------------- embedding GEMM + LayerNorm ----------------
__global__ void embed_ln(const float* __restrict__ x, const float* __restrict__ Wt,
                         const float* __restrict__ g, const float* __restrict__ b,
                         const float* __restrict__ pw, const float* __restrict__ sb,
                         float* __restrict__ F, float* __restrict__ C)
{
    __shared__ float lx[8][64];
    __shared__ float red[2][8][2];
    int c = threadIdx.x;
    int n0 = blockIdx.x * 8;
    for (int t = c; t < 8 * 64; t += 128) {
        lx[t >> 6][t & 63] = x[(size_t)(n0 + (t >> 6)) * 64 + (t & 63)];
    }
    __syncthreads();
    float acc[8];
#pragma unroll
    for (int m = 0; m < 8; m++) acc[m] = 0.f;
    for (int k = 0; k < 64; k++) {
        float w = Wt[k * 128 + c];
#pragma unroll
        for (int m = 0; m < 8; m++) acc[m] += lx[m][k] * w;
    }
    int lane = c & 63, wv = c >> 6;
#pragma unroll
    for (int m = 0; m < 8; m++) {
        float s1 = acc[m], s2 = acc[m] * acc[m];
        for (int off = 32; off; off >>= 1) { s1 += __shfl_xor(s1, off); s2 += __shfl_xor(s2, off); }
        if (lane == 0) { red[wv][m][0] = s1; red[wv][m][1] = s2; }
    }
    __syncthreads();
    float biassum = pw[0] * sb[c] + pw[1] * sb[128 + c];
    float gg = g[c], bb = b[c];
#pragma unroll
    for (int m = 0; m < 8; m++) {
        float s1 = red[0][m][0] + red[1][m][0];
        float s2 = red[0][m][1] + red[1][m][1];
        float mu  = s1 * (1.f / 128.f);
        float var = s2 * (1.f / 128.f) - mu * mu;
        float inv = rsqrtf(var + 1e-5f);
        float v = acc[m];
        size_t idx = (size_t)(n0 + m) * 128 + c;
        F[idx] = v + biassum;
        C[idx] = (v - mu) * inv * gg + bb;
    }
}

// ---------------- MFMA projection: out_bf = bf16(in @ W^T), dl/dr = in @ M ----------------
__global__ __launch_bounds__(256) void mfma_proj(
    const float* __restrict__ in,        // [NN][128] fp32
    const float* __restrict__ W,         // [128][128] fp32, [out][in]
    const float* __restrict__ M,         // [128][8] fp32
    unsigned short* __restrict__ out_bf, // [NN][128] bf16
    float4* __restrict__ dl4, float4* __restrict__ dr4)
{
    __shared__ unsigned short WL[16384];  // 128 rows x 16 chunks x 8 bf16, swizzled
    __shared__ float ML[1024];            // 128 x 8

    int t = threadIdx.x;
    for (int i = t; i < 2048; i += 256) {
        int n = i >> 4, c16 = i & 15;
        const float* src = W + n * 128 + c16 * 8;
        short8 v;
#pragma unroll
        for (int j = 0; j < 8; j++) v[j] = (short)f2bf(src[j]);
        *(short8*)&WL[(n * 16 + (c16 ^ (n & 15))) * 8] = v;
    }
    for (int i = t; i < 1024; i += 256) ML[i] = M[i];
    __syncthreads();

    int w = t >> 6, lane = t & 63;
    int ln = lane & 15, quad = lane >> 4;
    int rbase = blockIdx.x * 64 + w * 16;
    int row = rbase + ln;
    int arow = (row < NN) ? row : (NN - 1);

    short8 afrag[4];
    float p[8];
#pragma unroll
    for (int h = 0; h < 8; h++) p[h] = 0.f;
#pragma unroll
    for (int kc = 0; kc < 4; kc++) {
        int k0 = kc * 32 + quad * 8;
        const float* ap = in + (size_t)arow * 128 + k0;
        float av[8];
#pragma unroll
        for (int j = 0; j < 8; j++) av[j] = ap[j];
#pragma unroll
        for (int j = 0; j < 8; j++) {
            afrag[kc][j] = (short)f2bf(av[j]);
            const float* mrow = &ML[(k0 + j) * 8];
#pragma unroll
            for (int h = 0; h < 8; h++) p[h] += av[j] * mrow[h];
        }
    }
#pragma unroll
    for (int h = 0; h < 8; h++) {
        p[h] += __shfl_xor(p[h], 16);
        p[h] += __shfl_xor(p[h], 32);
    }
    if (quad == 0 && row < NN) {
        dl4[row] = make_float4(p[0], p[1], p[2], p[3]);
        dr4[row] = make_float4(p[4], p[5], p[6], p[7]);
    }

#pragma unroll
    for (int ct = 0; ct < 8; ct++) {
        floatx4 acc = {0.f, 0.f, 0.f, 0.f};
#pragma unroll
        for (int kc = 0; kc < 4; kc++) {
            int c16 = kc * 4 + quad;
            int n = ct * 16 + ln;
            short8 bfr = *(const short8*)&WL[(n * 16 + (c16 ^ ln)) * 8];
            acc = __builtin_amdgcn_mfma_f32_16x16x32_bf16(afrag[kc], bfr, acc, 0, 0, 0);
        }
#pragma unroll
        for (int r = 0; r < 4; r++) {
            int rr = rbase + quad * 4 + r;
            if (rr < NN) out_bf[(size_t)rr * 128 + ct * 16 + ln] = f2bf(acc[r]);
        }
    }
}

// ================= two-level bucket sort (8 edge lists) =================
__global__ void zero_bcnt(int* __restrict__ p)
{
    int i = blockIdx.x * 256 + threadIdx.x;
    if (i < 8 * NBKT) p[i] = 0;
}

__global__ void bucket_count(Ptr8 dst, int* __restrict__ bcnt)
{
    __shared__ int h[NBKT];
    int l = blockIdx.x / PA_B, cb = blockIdx.x % PA_B;
    const int* dp = dst.p[l];
    for (int i = threadIdx.x; i < NBKT; i += 256) h[i] = 0;
    __syncthreads();
    int e0 = cb * CHUNKA;
    for (int i = threadIdx.x; i < CHUNKA; i += 256) {
        int e = e0 + i;
        if (e < EE) atomicAdd(&h[dp[e] >> BSH], 1);
    }
    __syncthreads();
    for (int i = threadIdx.x; i < NBKT; i += 256)
        if (h[i]) atomicAdd(&bcnt[l * NBKT + i], h[i]);
}

__global__ void bucket_scan(const int* __restrict__ bcnt, int* __restrict__ bstart,
                            int* __restrict__ bcur)
{
    __shared__ int sh[NBKT];
    int l = blockIdx.x;
    for (int i = threadIdx.x; i < NBKT; i += 256) sh[i] = bcnt[l * NBKT + i];
    __syncthreads();
    if (threadIdx.x == 0) {
        int acc = 0;
        for (int i = 0; i < NBKT; i++) { int t = sh[i]; sh[i] = acc; acc += t; }
    }
    __syncthreads();
    for (int i = threadIdx.x; i < NBKT; i += 256) {
        bstart[l * (NBKT + 1) + i] = sh[i];
        bcur[l * NBKT + i] = sh[i];
    }
    if (threadIdx.x == 0) bstart[l * (NBKT + 1) + NBKT] = EE;
}

__global__ void bucket_place(Ptr8 src, Ptr8 dst, int* __restrict__ bcur,
                             unsigned* __restrict__ recs)
{
    __shared__ int h[NBKT];
    __shared__ int base[NBKT];
    int l = blockIdx.x / PA_B, cb = blockIdx.x % PA_B;
    const int* sp = src.p[l];
    const int* dp = dst.p[l];
    for (int i = threadIdx.x; i < NBKT; i += 256) h[i] = 0;
    __syncthreads();
    int e0 = cb * CHUNKA;
    for (int i = threadIdx.x; i < CHUNKA; i += 256) {
        int e = e0 + i;
        if (e < EE) atomicAdd(&h[dp[e] >> BSH], 1);
    }
    __syncthreads();
    for (int i = threadIdx.x; i < NBKT; i += 256) {
        int c = h[i];
        base[i] = c ? atomicAdd(&bcur[l * NBKT + i], c) : 0;
        h[i] = 0;
    }
    __syncthreads();
    unsigned* rl = recs + (size_t)l * EE;
    for (int i = threadIdx.x; i < CHUNKA; i += 256) {
        int e = e0 + i;
        if (e >= EE) continue;
        int d = dp[e];
        int b = d >> BSH;
        int pos = base[b] + atomicAdd(&h[b], 1);
        rl[pos] = ((unsigned)sp[e] << 16) | (unsigned)d;
    }
}

// one block per 512-dst bucket: stage recs in LDS, parallel scan, exact placement
__global__ __launch_bounds__(256) void bucket_final(
    const unsigned* __restrict__ recs, const int* __restrict__ bstart,
    int* __restrict__ starts8, int* __restrict__ counts8,
    unsigned short* __restrict__ sortedU)
{
    __shared__ unsigned R[FCAP];
    __shared__ int cnt[512];
    __shared__ int cur[512];
    __shared__ int psum[256];
    int l = blockIdx.x / NBKT, b = blockIdx.x % NBKT;
    int d0 = b << BSH;
    int nd = min(512, NN - d0);
    int ebase = bstart[l * (NBKT + 1) + b];
    int ecnt  = bstart[l * (NBKT + 1) + b + 1] - ebase;
    const unsigned* rp = recs + (size_t)l * EE + ebase;
    int t = threadIdx.x;
    bool inLds = (ecnt <= FCAP);

    for (int i = t; i < 512; i += 256) cnt[i] = 0;
    __syncthreads();
    for (int i = t; i < ecnt; i += 256) {
        unsigned r = rp[i];
        if (inLds) R[i] = r;
        atomicAdd(&cnt[(r & 0xffffu) - d0], 1);
    }
    __syncthreads();
    // exclusive scan of cnt[512]: pairwise partials + 256-ladder
    int s0 = cnt[2 * t] + cnt[2 * t + 1];
    psum[t] = s0;
    __syncthreads();
    for (int off = 1; off < 256; off <<= 1) {
        int x = (t >= off) ? psum[t - off] : 0;
        __syncthreads();
        psum[t] += x;
        __syncthreads();
    }
    int excl = psum[t] - s0;
    cur[2 * t] = excl;
    cur[2 * t + 1] = excl + cnt[2 * t];
    __syncthreads();
    for (int i = t; i < nd; i += 256) {
        starts8[l * NN + d0 + i] = ebase + cur[i];
        counts8[l * NN + d0 + i] = cnt[i];
    }
    __syncthreads();
    unsigned short* so = sortedU + (size_t)l * EE + ebase;
    for (int i = t; i < ecnt; i += 256) {
        unsigned r = inLds ? R[i] : rp[i];
        int dloc = (int)(r & 0xffffu) - d0;
        int pos = atomicAdd(&cur[dloc], 1);
        so[pos] = (unsigned short)(r >> 16);
    }
}

// ---------------- fused pair aggregation ----------------
// 256 threads = 4 waves = 2 dsts x 2 segments. Each wave: wave-local softmax
// (shfl butterfly, no LDS reduction) + 4-edge-per-iter bf16 gather for its
// (dst, segment). One acc access per dst for the PAIR of segments.
// mode 0: acc += segA+segB (self residual). mode 1: acc = bias0+bias1+segA+segB.
__global__ __launch_bounds__(256) void agg_fused(
    SegArg A, SegArg B,
    const float* __restrict__ bias0, const float* __restrict__ bias1,
    float* __restrict__ acc, int mode)
{
    __shared__ float4 exSh[4][CAP];
    __shared__ int    sSh[4][CAP + 4];
    __shared__ float  wSh[4][CAP + 4];
    __shared__ float  cmb[4][128];

    int t = threadIdx.x;
    int slot = t >> 6;            // 0..3
    int w = slot & 1;             // segment within pair
    int dh = slot >> 1;           // which of the 2 dsts
    int lane = t & 63;
    int d = blockIdx.x * 2 + dh;

    const SegArg S = w ? B : A;   // wave-uniform select

    int base = S.starts[d];
    int k = S.counts[d];
    int kTot = k + S.hasLoop;

    float4 ad = *(const float4*)(S.adst + (size_t)d * 4);
    float p0 = 0.f, p1 = 0.f, p2 = 0.f, p3 = 0.f;
    for (int i = lane; i < kTot; i += 64) {
        int s = (i < k) ? (int)S.srt[base + i] : d;
        float4 as = *(const float4*)(S.asrc + (size_t)s * 4);
        float v0 = ad.x + as.x, v1 = ad.y + as.y, v2 = ad.z + as.z, v3 = ad.w + as.w;
        v0 = v0 > 0.f ? v0 : NEG * v0;
        v1 = v1 > 0.f ? v1 : NEG * v1;
        v2 = v2 > 0.f ? v2 : NEG * v2;
        v3 = v3 > 0.f ? v3 : NEG * v3;
        float e0 = __expf(v0), e1 = __expf(v1), e2 = __expf(v2), e3 = __expf(v3);
        if (i < CAP) { exSh[slot][i] = make_float4(e0, e1, e2, e3); sSh[slot][i] = s; }
        p0 += e0; p1 += e1; p2 += e2; p3 += e3;
    }
#pragma unroll
    for (int off = 32; off; off >>= 1) {
        p0 += __shfl_xor(p0, off); p1 += __shfl_xor(p1, off);
        p2 += __shfl_xor(p2, off); p3 += __shfl_xor(p3, off);
    }
    float scale = 0.25f * (S.pw ? S.pw[S.pwi] : 1.0f);
    float den0 = p0 + 1e-16f, den1 = p1 + 1e-16f;
    float den2 = p2 + 1e-16f, den3 = p3 + 1e-16f;

    // per-segment normalized weights into LDS (covers min(kTot, CAP))
    int kW = kTot < CAP ? kTot : CAP;
    for (int i = lane; i < kW; i += 64) {
        float4 ex = exSh[slot][i];
        wSh[slot][i] = scale * (ex.x / den0 + ex.y / den1 + ex.z / den2 + ex.w / den3);
    }
    if (kTot <= CAP) {
        int nPad = (kTot + 3) & ~3;
        for (int i = kTot + lane; i < nPad; i += 64) { wSh[slot][i] = 0.f; sSh[slot][i] = 0; }
    }
    __syncthreads();   // unconditional: all 4 waves

    if (kTot <= CAP) {
        // main path: 4 edges/iter/wave, 16 lanes x ushort8 = full 128-ch row
        int g = lane >> 4, c8 = lane & 15;
        float a[8];
#pragma unroll
        for (int i = 0; i < 8; i++) a[i] = 0.f;
        int nIter = (kTot + 3) >> 2;
        for (int it = 0; it < nIter; ++it) {
            int j = it * 4 + g;
            float wgt = wSh[slot][j];
            int s = sSh[slot][j];
            ushort8 v = *(const ushort8*)(S.feats + (size_t)s * 128 + c8 * 8);
#pragma unroll
            for (int i = 0; i < 8; i++)
                a[i] += wgt * __uint_as_float((unsigned)(unsigned short)v[i] << 16);
        }
#pragma unroll
        for (int i = 0; i < 8; i++) {
            a[i] += __shfl_xor(a[i], 16);
            a[i] += __shfl_xor(a[i], 32);
        }
        if (lane < 16) {
#pragma unroll
            for (int i = 0; i < 8; i++) cmb[slot][lane * 8 + i] = a[i];
        }
    } else {
        // rare fallback: degree > CAP, serial over edges within the wave
        float a0 = 0.f, a1 = 0.f;
        for (int j = 0; j < kTot; ++j) {
            float wgt; int s;
            if (j < CAP) { wgt = wSh[slot][j]; s = sSh[slot][j]; }
            else {
                s = (j < k) ? (int)S.srt[base + j] : d;
                float4 as = *(const float4*)(S.asrc + (size_t)s * 4);
                float v0 = ad.x + as.x, v1 = ad.y + as.y, v2 = ad.z + as.z, v3 = ad.w + as.w;
                v0 = v0 > 0.f ? v0 : NEG * v0;
                v1 = v1 > 0.f ? v1 : NEG * v1;
                v2 = v2 > 0.f ? v2 : NEG * v2;
                v3 = v3 > 0.f ? v3 : NEG * v3;
                wgt = scale * (__expf(v0) / den0 + __expf(v1) / den1 +
                               __expf(v2) / den2 + __expf(v3) / den3);
            }
            unsigned v = *(const unsigned*)(S.feats + (size_t)s * 128 + 2 * lane);
            a0 += wgt * __uint_as_float(v << 16);
            a1 += wgt * __uint_as_float(v & 0xffff0000u);
        }
        cmb[slot][2 * lane] = a0;
        cmb[slot][2 * lane + 1] = a1;
    }
    __syncthreads();

    // combine pair, single acc access per dst
    {
        int dh2 = t >> 7;             // 0/1: which dst
        int c = t & 127;
        int dd = blockIdx.x * 2 + dh2;
        float sum = cmb[dh2 * 2][c] + cmb[dh2 * 2 + 1][c];
        size_t idx = (size_t)dd * 128 + c;
        if (mode) acc[idx] = bias0[c] + bias1[c] + sum;
        else      acc[idx] += sum;
    }
}

extern "C" void kernel_launch(void* const* d_in, const int* in_sizes, int n_in,
                              void* d_out, int out_size, void* d_ws, size_t ws_size,
                              hipStream_t stream)
{
    const float* x_var   = (const float*)d_in[0];
    const float* x_cls   = (const float*)d_in[1];
    const int*   mp_var  = (const int*)d_in[2];
    const int*   mp_cls  = (const int*)d_in[3];
    const int*   adj_pos = (const int*)d_in[4];
    const int*   adj_neg = (const int*)d_in[5];
    const float* W_var_emb = (const float*)d_in[6];
    const float* W_cls_emb = (const float*)d_in[7];
    const float* ln_var_g = (const float*)d_in[8];
    const float* ln_var_b = (const float*)d_in[9];
    const float* ln_cls_g = (const float*)d_in[10];
    const float* ln_cls_b = (const float*)d_in[11];
    const float* var_pw = (const float*)d_in[12];
    const float* cls_pw = (const float*)d_in[13];
    const float* sv_W  = (const float*)d_in[14];
    const float* sv_al = (const float*)d_in[15];
    const float* sv_ar = (const float*)d_in[16];
    const float* sv_b  = (const float*)d_in[17];
    const float* sc_W  = (const float*)d_in[18];
    const float* sc_al = (const float*)d_in[19];
    const float* sc_ar = (const float*)d_in[20];
    const float* sc_b  = (const float*)d_in[21];
    const float* cp_Wl = (const float*)d_in[22];
    const float* cp_Wr = (const float*)d_in[23];
    const float* cp_al = (const float*)d_in[24];
    const float* cp_ar = (const float*)d_in[25];
    const float* cp_b  = (const float*)d_in[26];
    const float* cn_Wl = (const float*)d_in[27];
    const float* cn_Wr = (const float*)d_in[28];
    const float* cn_al = (const float*)d_in[29];
    const float* cn_ar = (const float*)d_in[30];
    const float* cn_b  = (const float*)d_in[31];

    float* out0 = (float*)d_out;
    float* out1 = out0 + (size_t)NN * 128;

    float* ws = (float*)d_ws;
    size_t off = 0;
    auto alloc = [&](size_t n) { float* p = ws + off; off += n; return p; };
    float* Wt   = alloc(16384);
    float* Mbuf = alloc(8 * 1024);
    float* F   = alloc((size_t)NN * 128);
    float* G   = alloc((size_t)NN * 128);
    float* C   = alloc((size_t)NN * 128);   // hv; reused as 2x bf16 feats after self-proj
    float* D   = alloc((size_t)NN * 128);   // hc
    unsigned short* B1 = (unsigned short*)alloc((size_t)NN * 64);  // bf16 [NN][128]
    unsigned short* B2 = (unsigned short*)alloc((size_t)NN * 64);
    float* dl   = alloc(NN * 4);
    float* dr   = alloc(NN * 4);
    float* dl2  = alloc(NN * 4);
    float* dr2  = alloc(NN * 4);
    float* dl3  = alloc(NN * 4);
    float* dr3  = alloc(NN * 4);
    float* dl4  = alloc(NN * 4);
    float* dr4  = alloc(NN * 4);
    int* counts8 = (int*)alloc(8 * NN);
    int* starts8 = (int*)alloc(8 * NN);
    int* bcnt    = (int*)alloc(8 * NBKT);
    int* bstart  = (int*)alloc(8 * (NBKT + 1));
    int* bcur    = (int*)alloc(8 * NBKT);
    unsigned* recs = (unsigned*)alloc((size_t)8 * EE);
    unsigned short* sortedU = (unsigned short*)alloc((size_t)4 * EE);

    // carve two bf16 feats buffers out of C (dead after self projections)
    unsigned short* Pc = (unsigned short*)C;                       // [NN][128] bf16
    unsigned short* Pd = (unsigned short*)C + (size_t)NN * 128;    // [NN][128] bf16

    const float* WtEv = Wt;
    const float* WtEc = Wt + 8192;

    Ptr8 srcP, dstP;
    srcP.p[0] = mp_var;            dstP.p[0] = mp_var + EE;
    srcP.p[1] = mp_var + 2 * EE;   dstP.p[1] = mp_var + 3 * EE;
    srcP.p[2] = mp_cls;            dstP.p[2] = mp_cls + EE;
    srcP.p[3] = mp_cls + 2 * EE;   dstP.p[3] = mp_cls + 3 * EE;
    srcP.p[4] = adj_pos;           dstP.p[4] = adj_pos + EE;
    srcP.p[5] = adj_pos + EE;      dstP.p[5] = adj_pos;
    srcP.p[6] = adj_neg;           dstP.p[6] = adj_neg + EE;
    srcP.p[7] = adj_neg + EE;      dstP.p[7] = adj_neg;

    MArgs ma;
    ma.w[0] = sv_W;           ma.al[0] = sv_al;        ma.ar[0] = sv_ar;
    ma.w[1] = sv_W + 16384;   ma.al[1] = sv_al + 512;  ma.ar[1] = sv_ar + 512;
    ma.w[2] = sc_W;           ma.al[2] = sc_al;        ma.ar[2] = sc_ar;
    ma.w[3] = sc_W + 16384;   ma.al[3] = sc_al + 512;  ma.ar[3] = sc_ar + 512;
    ma.w[4] = cp_Wl;          ma.al[4] = cp_al;        ma.ar[4] = cp_ar;
    ma.w[5] = cp_Wr;          ma.al[5] = cp_al;        ma.ar[5] = cp_ar;
    ma.w[6] = cn_Wl;          ma.al[6] = cn_al;        ma.ar[6] = cn_ar;
    ma.w[7] = cn_Wr;          ma.al[7] = cn_al;        ma.ar[7] = cn_ar;

    // ---- two-level bucket sort of all 8 edge lists ----
    zero_bcnt<<<(8 * NBKT + 255) / 256, 256, 0, stream>>>(bcnt);
    bucket_count<<<8 * PA_B, 256, 0, stream>>>(dstP, bcnt);
    bucket_scan<<<8, 256, 0, stream>>>(bcnt, bstart, bcur);
    bucket_place<<<8 * PA_B, 256, 0, stream>>>(srcP, dstP, bcur, recs);
    bucket_final<<<8 * NBKT, 256, 0, stream>>>(recs, bstart, starts8, counts8, sortedU);

    transpose_emb<<<64, 256, 0, stream>>>(W_var_emb, W_cls_emb, Wt);
    make_M<<<8, 256, 0, stream>>>(ma, Mbuf);
    embed_ln<<<NN / 8, 128, 0, stream>>>(x_var, WtEv, ln_var_g, ln_var_b, var_pw, sv_b, F, C);
    embed_ln<<<NN / 8, 128, 0, stream>>>(x_cls, WtEc, ln_cls_g, ln_cls_b, cls_pw, sc_b, G, D);

    const int PB = (NN + 63) / 64;

    // ---- self attention: fuse p=0/p=1 into one agg per side ----
    for (int side = 0; side < 2; ++side) {
        const float* h   = side ? D : C;
        float*       accp = side ? G : F;
        const float* pw  = side ? cls_pw : var_pw;
        int s0 = side * 2, s1 = side * 2 + 1;
        mfma_proj<<<PB, 256, 0, stream>>>(h, ma.w[s0], Mbuf + s0 * 1024,
                                          B1, (float4*)dl, (float4*)dr);
        mfma_proj<<<PB, 256, 0, stream>>>(h, ma.w[s1], Mbuf + s1 * 1024,
                                          B2, (float4*)dl2, (float4*)dr2);
        SegArg SA, SB;
        SA.starts = starts8 + s0 * NN; SA.counts = counts8 + s0 * NN;
        SA.srt = sortedU + (size_t)s0 * EE;
        SA.adst = dl;  SA.asrc = dr;  SA.feats = B1; SA.pw = pw; SA.pwi = 0; SA.hasLoop = 1;
        SB.starts = starts8 + s1 * NN; SB.counts = counts8 + s1 * NN;
        SB.srt = sortedU + (size_t)s1 * EE;
        SB.adst = dl2; SB.asrc = dr2; SB.feats = B2; SB.pw = pw; SB.pwi = 1; SB.hasLoop = 1;
        agg_fused<<<NN / 2, 256, 0, stream>>>(SA, SB, cp_b, cn_b, accp, 0);
    }

    // ---- cross attention: all 4 projections, then fuse pos/neg per output ----
    mfma_proj<<<PB, 256, 0, stream>>>(F, ma.w[4], Mbuf + 4 * 1024,
                                      B1, (float4*)dl, (float4*)dr);    // pos: al, ar_
    mfma_proj<<<PB, 256, 0, stream>>>(G, ma.w[5], Mbuf + 5 * 1024,
                                      B2, (float4*)dl2, (float4*)dr2);  // pos: al_, ar
    mfma_proj<<<PB, 256, 0, stream>>>(F, ma.w[6], Mbuf + 6 * 1024,
                                      Pc, (float4*)dl3, (float4*)dr3);  // neg: al, ar_
    mfma_proj<<<PB, 256, 0, stream>>>(G, ma.w[7], Mbuf + 7 * 1024,
                                      Pd, (float4*)dl4, (float4*)dr4);  // neg: al_, ar

    {   // out0 (var nodes): seg4 (pos) + seg6 (neg), bias written in-kernel
        SegArg SA, SB;
        SA.starts = starts8 + 4 * NN; SA.counts = counts8 + 4 * NN;
        SA.srt = sortedU + (size_t)4 * EE;
        SA.adst = dl;  SA.asrc = dr2; SA.feats = B2; SA.pw = nullptr; SA.pwi = 0; SA.hasLoop = 0;
        SB.starts = starts8 + 6 * NN; SB.counts = counts8 + 6 * NN;
        SB.srt = sortedU + (size_t)6 * EE;
        SB.adst = dl3; SB.asrc = dr4; SB.feats = Pd; SB.pw = nullptr; SB.pwi = 0; SB.hasLoop = 0;
        agg_fused<<<NN / 2, 256, 0, stream>>>(SA, SB, cp_b, cn_b, out0, 1);
    }
    {   // out1 (cls nodes): seg5 (pos) + seg7 (neg)
        SegArg SA, SB;
        SA.starts = starts8 + 5 * NN; SA.counts = counts8 + 5 * NN;
        SA.srt = sortedU + (size_t)5 * EE;
        SA.adst = dl2; SA.asrc = dr;  SA.feats = B1; SA.pw = nullptr; SA.pwi = 0; SA.hasLoop = 0;
        SB.starts = starts8 + 7 * NN; SB.counts = counts8 + 7 * NN;
        SB.srt = sortedU + (size_t)7 * EE;
        SB.adst = dl4; SB.asrc = dr3; SB.feats = Pc; SB.pw = nullptr; SB.pwi = 0; SB.hasLoop = 0;
        agg_fused<<<NN / 2, 256, 0, stream>>>(SA, SB, cp_b, cn_b, out1, 1);
    }
}

// Round 2
// 754.432 us; speedup vs baseline: 1.2466x; 1.0239x over previous
//
#include <hip/hip_runtime.h>
#include <hip/hip_bf16.h>

#define NN 50000
#define EE 640000
#define NEG 0.2f
#define CAP 128          // per-segment cache; degree ~ Poisson(12.8), P(k>128) ~ 0

#define BSH 9                          // 512 dsts per bucket
#define NBKT 98                        // ceil(NN/512)
#define FCAP 7168                      // LDS record stage in bucket_final
#define CHUNKA 8192
#define PA_B 79                        // ceil(EE/CHUNKA)

struct Ptr8 { const int* p[8]; };
struct MArgs { const float* w[8]; const float* al[8]; const float* ar[8]; };

struct SegArg {
    const int* starts;
    const int* counts;
    const unsigned short* srt;
    const float* adst;
    const float* asrc;
    const unsigned short* feats;
    const float* pw;
    int pwi;
    int hasLoop;
};

typedef __attribute__((ext_vector_type(8))) short short8;
typedef __attribute__((ext_vector_type(8))) unsigned short ushort8;
typedef __attribute__((ext_vector_type(4))) float floatx4;

__device__ __forceinline__ unsigned short f2bf(float x) {
    unsigned b = __float_as_uint(x);
    b = b + 0x7fffu + ((b >> 16) & 1u);   // RNE
    return (unsigned short)(b >> 16);
}

// ---------------- transpose embedding weights ----------------
__global__ void transpose_emb(const float* __restrict__ wev, const float* __restrict__ wec,
                              float* __restrict__ out)
{
    int i = blockIdx.x * 256 + threadIdx.x;
    if (i < 8192) { out[i] = wev[(i & 127) * 64 + (i >> 7)]; return; }
    if (i < 16384) { int j = i - 8192; out[i] = wec[(j & 127) * 64 + (j >> 7)]; }
}

// ---------------- M[p] = W_p^T @ [attL | attR]  (128x8 per projection) ----------------
__global__ void make_M(MArgs a, float* __restrict__ Mbuf)
{
    int b = blockIdx.x;
    const float* W  = a.w[b];
    const float* AL = a.al[b];
    const float* AR = a.ar[b];
    for (int e = threadIdx.x; e < 1024; e += 256) {
        int k = e >> 3, h = e & 7;
        const float* att = (h < 4) ? AL : AR;
        int hh = h & 3;
        float s = 0.f;
        for (int c = 0; c < 128; c++) s += W[c * 128 + k] * att[c * 4 + hh];
        Mbuf[b * 1024 + e] = s;
    }
}

// ---------------- embedding GEMM + LayerNorm ----------------
__global__ void embed_ln(const float* __restrict__ x, const float* __restrict__ Wt,
                         const float* __restrict__ g, const float* __restrict__ b,
                         const float* __restrict__ pw, const float* __restrict__ sb,
                         float* __restrict__ F, float* __restrict__ C)
{
    __shared__ float lx[8][64];
    __shared__ float red[2][8][2];
    int c = threadIdx.x;
    int n0 = blockIdx.x * 8;
    for (int t = c; t < 8 * 64; t += 128) {
        lx[t >> 6][t & 63] = x[(size_t)(n0 + (t >> 6)) * 64 + (t & 63)];
    }
    __syncthreads();
    float acc[8];
#pragma unroll
    for (int m = 0; m < 8; m++) acc[m] = 0.f;
    for (int k = 0; k < 64; k++) {
        float w = Wt[k * 128 + c];
#pragma unroll
        for (int m = 0; m < 8; m++) acc[m] += lx[m][k] * w;
    }
    int lane = c & 63, wv = c >> 6;
#pragma unroll
    for (int m = 0; m < 8; m++) {
        float s1 = acc[m], s2 = acc[m] * acc[m];
        for (int off = 32; off; off >>= 1) { s1 += __shfl_xor(s1, off); s2 += __shfl_xor(s2, off); }
        if (lane == 0) { red[wv][m][0] = s1; red[wv][m][1] = s2; }
    }
    __syncthreads();
    float biassum = pw[0] * sb[c] + pw[1] * sb[128 + c];
    float gg = g[c], bb = b[c];
#pragma unroll
    for (int m = 0; m < 8; m++) {
        float s1 = red[0][m][0] + red[1][m][0];
        float s2 = red[0][m][1] + red[1][m][1];
        float mu  = s1 * (1.f / 128.f);
        float var = s2 * (1.f / 128.f) - mu * mu;
        float inv = rsqrtf(var + 1e-5f);
        float v = acc[m];
        size_t idx = (size_t)(n0 + m) * 128 + c;
        F[idx] = v + biassum;
        C[idx] = (v - mu) * inv * gg + bb;
    }
}

// ---------------- fused pair projection ----------------
// Two projections of the SAME input: read input rows once (registers),
// both M-projections in one pass, two MFMA phases (WL reloaded between
// barriers so LDS stays 34KB -> occupancy unchanged vs single proj).
__device__ __forceinline__ void stage_W(const float* __restrict__ W,
                                        unsigned short* __restrict__ WL, int t)
{
    for (int i = t; i < 2048; i += 256) {
        int n = i >> 4, c16 = i & 15;
        const float* src = W + n * 128 + c16 * 8;
        short8 v;
#pragma unroll
        for (int j = 0; j < 8; j++) v[j] = (short)f2bf(src[j]);
        *(short8*)&WL[(n * 16 + (c16 ^ (n & 15))) * 8] = v;
    }
}

__global__ __launch_bounds__(256) void mfma_proj2(
    const float* __restrict__ in,        // [NN][128] fp32
    const float* __restrict__ W0, const float* __restrict__ W1,
    const float* __restrict__ M0, const float* __restrict__ M1,
    unsigned short* __restrict__ ob0, unsigned short* __restrict__ ob1,
    float4* __restrict__ dl0, float4* __restrict__ dr0,
    float4* __restrict__ dl1, float4* __restrict__ dr1)
{
    __shared__ unsigned short WL[16384];  // 128 rows x 16 chunks x 8 bf16, swizzled
    __shared__ float ML[2048];            // 2 x 128 x 8

    int t = threadIdx.x;
    stage_W(W0, WL, t);
    for (int i = t; i < 1024; i += 256) { ML[i] = M0[i]; ML[1024 + i] = M1[i]; }
    __syncthreads();

    int w = t >> 6, lane = t & 63;
    int ln = lane & 15, quad = lane >> 4;
    int rbase = blockIdx.x * 64 + w * 16;
    int row = rbase + ln;
    int arow = (row < NN) ? row : (NN - 1);

    short8 afrag[4];
    float p[16];
#pragma unroll
    for (int h = 0; h < 16; h++) p[h] = 0.f;
#pragma unroll
    for (int kc = 0; kc < 4; kc++) {
        int k0 = kc * 32 + quad * 8;
        const float* ap = in + (size_t)arow * 128 + k0;
        float av[8];
#pragma unroll
        for (int j = 0; j < 8; j++) av[j] = ap[j];
#pragma unroll
        for (int j = 0; j < 8; j++) {
            afrag[kc][j] = (short)f2bf(av[j]);
            const float* m0 = &ML[(k0 + j) * 8];
            const float* m1 = &ML[1024 + (k0 + j) * 8];
#pragma unroll
            for (int h = 0; h < 8; h++) { p[h] += av[j] * m0[h]; p[8 + h] += av[j] * m1[h]; }
        }
    }
#pragma unroll
    for (int h = 0; h < 16; h++) {
        p[h] += __shfl_xor(p[h], 16);
        p[h] += __shfl_xor(p[h], 32);
    }
    if (quad == 0 && row < NN) {
        dl0[row] = make_float4(p[0], p[1], p[2], p[3]);
        dr0[row] = make_float4(p[4], p[5], p[6], p[7]);
        dl1[row] = make_float4(p[8], p[9], p[10], p[11]);
        dr1[row] = make_float4(p[12], p[13], p[14], p[15]);
    }

    // ---- phase 0: MFMA with W0 ----
#pragma unroll
    for (int ct = 0; ct < 8; ct++) {
        floatx4 acc = {0.f, 0.f, 0.f, 0.f};
#pragma unroll
        for (int kc = 0; kc < 4; kc++) {
            int c16 = kc * 4 + quad;
            int n = ct * 16 + ln;
            short8 bfr = *(const short8*)&WL[(n * 16 + (c16 ^ ln)) * 8];
            acc = __builtin_amdgcn_mfma_f32_16x16x32_bf16(afrag[kc], bfr, acc, 0, 0, 0);
        }
#pragma unroll
        for (int r = 0; r < 4; r++) {
            int rr = rbase + quad * 4 + r;
            if (rr < NN) ob0[(size_t)rr * 128 + ct * 16 + ln] = f2bf(acc[r]);
        }
    }
    __syncthreads();
    stage_W(W1, WL, t);
    __syncthreads();
    // ---- phase 1: MFMA with W1 ----
#pragma unroll
    for (int ct = 0; ct < 8; ct++) {
        floatx4 acc = {0.f, 0.f, 0.f, 0.f};
#pragma unroll
        for (int kc = 0; kc < 4; kc++) {
            int c16 = kc * 4 + quad;
            int n = ct * 16 + ln;
            short8 bfr = *(const short8*)&WL[(n * 16 + (c16 ^ ln)) * 8];
            acc = __builtin_amdgcn_mfma_f32_16x16x32_bf16(afrag[kc], bfr, acc, 0, 0, 0);
        }
#pragma unroll
        for (int r = 0; r < 4; r++) {
            int rr = rbase + quad * 4 + r;
            if (rr < NN) ob1[(size_t)rr * 128 + ct * 16 + ln] = f2bf(acc[r]);
        }
    }
}

// ================= two-level bucket sort (8 edge lists) =================
__global__ void zero_bcnt(int* __restrict__ p)
{
    int i = blockIdx.x * 256 + threadIdx.x;
    if (i < 8 * NBKT) p[i] = 0;
}

__global__ void bucket_count(Ptr8 dst, int* __restrict__ bcnt)
{
    __shared__ int h[NBKT];
    int l = blockIdx.x / PA_B, cb = blockIdx.x % PA_B;
    const int* dp = dst.p[l];
    for (int i = threadIdx.x; i < NBKT; i += 256) h[i] = 0;
    __syncthreads();
    int e0 = cb * CHUNKA;
    for (int i = threadIdx.x; i < CHUNKA; i += 256) {
        int e = e0 + i;
        if (e < EE) atomicAdd(&h[dp[e] >> BSH], 1);
    }
    __syncthreads();
    for (int i = threadIdx.x; i < NBKT; i += 256)
        if (h[i]) atomicAdd(&bcnt[l * NBKT + i], h[i]);
}

__global__ void bucket_scan(const int* __restrict__ bcnt, int* __restrict__ bstart,
                            int* __restrict__ bcur)
{
    __shared__ int sh[NBKT];
    int l = blockIdx.x;
    for (int i = threadIdx.x; i < NBKT; i += 256) sh[i] = bcnt[l * NBKT + i];
    __syncthreads();
    if (threadIdx.x == 0) {
        int acc = 0;
        for (int i = 0; i < NBKT; i++) { int t = sh[i]; sh[i] = acc; acc += t; }
    }
    __syncthreads();
    for (int i = threadIdx.x; i < NBKT; i += 256) {
        bstart[l * (NBKT + 1) + i] = sh[i];
        bcur[l * NBKT + i] = sh[i];
    }
    if (threadIdx.x == 0) bstart[l * (NBKT + 1) + NBKT] = EE;
}

__global__ void bucket_place(Ptr8 src, Ptr8 dst, int* __restrict__ bcur,
                             unsigned* __restrict__ recs)
{
    __shared__ int h[NBKT];
    __shared__ int base[NBKT];
    int l = blockIdx.x / PA_B, cb = blockIdx.x % PA_B;
    const int* sp = src.p[l];
    const int* dp = dst.p[l];
    for (int i = threadIdx.x; i < NBKT; i += 256) h[i] = 0;
    __syncthreads();
    int e0 = cb * CHUNKA;
    for (int i = threadIdx.x; i < CHUNKA; i += 256) {
        int e = e0 + i;
        if (e < EE) atomicAdd(&h[dp[e] >> BSH], 1);
    }
    __syncthreads();
    for (int i = threadIdx.x; i < NBKT; i += 256) {
        int c = h[i];
        base[i] = c ? atomicAdd(&bcur[l * NBKT + i], c) : 0;
        h[i] = 0;
    }
    __syncthreads();
    unsigned* rl = recs + (size_t)l * EE;
    for (int i = threadIdx.x; i < CHUNKA; i += 256) {
        int e = e0 + i;
        if (e >= EE) continue;
        int d = dp[e];
        int b = d >> BSH;
        int pos = base[b] + atomicAdd(&h[b], 1);
        rl[pos] = ((unsigned)sp[e] << 16) | (unsigned)d;
    }
}

// one block per 512-dst bucket: stage recs in LDS, parallel scan, exact placement
__global__ __launch_bounds__(256) void bucket_final(
    const unsigned* __restrict__ recs, const int* __restrict__ bstart,
    int* __restrict__ starts8, int* __restrict__ counts8,
    unsigned short* __restrict__ sortedU)
{
    __shared__ unsigned R[FCAP];
    __shared__ int cnt[512];
    __shared__ int cur[512];
    __shared__ int psum[256];
    int l = blockIdx.x / NBKT, b = blockIdx.x % NBKT;
    int d0 = b << BSH;
    int nd = min(512, NN - d0);
    int ebase = bstart[l * (NBKT + 1) + b];
    int ecnt  = bstart[l * (NBKT + 1) + b + 1] - ebase;
    const unsigned* rp = recs + (size_t)l * EE + ebase;
    int t = threadIdx.x;
    bool inLds = (ecnt <= FCAP);

    for (int i = t; i < 512; i += 256) cnt[i] = 0;
    __syncthreads();
    for (int i = t; i < ecnt; i += 256) {
        unsigned r = rp[i];
        if (inLds) R[i] = r;
        atomicAdd(&cnt[(r & 0xffffu) - d0], 1);
    }
    __syncthreads();
    // exclusive scan of cnt[512]: pairwise partials + 256-ladder
    int s0 = cnt[2 * t] + cnt[2 * t + 1];
    psum[t] = s0;
    __syncthreads();
    for (int off = 1; off < 256; off <<= 1) {
        int x = (t >= off) ? psum[t - off] : 0;
        __syncthreads();
        psum[t] += x;
        __syncthreads();
    }
    int excl = psum[t] - s0;
    cur[2 * t] = excl;
    cur[2 * t + 1] = excl + cnt[2 * t];
    __syncthreads();
    for (int i = t; i < nd; i += 256) {
        starts8[l * NN + d0 + i] = ebase + cur[i];
        counts8[l * NN + d0 + i] = cnt[i];
    }
    __syncthreads();
    unsigned short* so = sortedU + (size_t)l * EE + ebase;
    for (int i = t; i < ecnt; i += 256) {
        unsigned r = inLds ? R[i] : rp[i];
        int dloc = (int)(r & 0xffffu) - d0;
        int pos = atomicAdd(&cur[dloc], 1);
        so[pos] = (unsigned short)(r >> 16);
    }
}

// ---------------- fused pair aggregation ----------------
// 256 threads = 4 waves = 2 dsts x 2 segments. Each wave: wave-local softmax
// (shfl butterfly), hoisted reciprocal weights (4 divides per WAVE, not per
// edge), 8-edge-per-iter bf16 gather (2 loads in flight per lane). One acc
// access per dst for the PAIR of segments.
// mode 0: acc += segA+segB (self residual). mode 1: acc = bias0+bias1+segA+segB.
__global__ __launch_bounds__(256) void agg_fused(
    SegArg A, SegArg B,
    const float* __restrict__ bias0, const float* __restrict__ bias1,
    float* __restrict__ acc, int mode)
{
    __shared__ float4 exSh[4][CAP];
    __shared__ int    sSh[4][CAP + 8];
    __shared__ float  wSh[4][CAP + 8];
    __shared__ float  cmb[4][128];

    int t = threadIdx.x;
    int slot = t >> 6;            // 0..3
    int w = slot & 1;             // segment within pair
    int dh = slot >> 1;           // which of the 2 dsts
    int lane = t & 63;
    int d = blockIdx.x * 2 + dh;

    const SegArg S = w ? B : A;   // wave-uniform select

    int base = S.starts[d];
    int k = S.counts[d];
    int kTot = k + S.hasLoop;

    float4 ad = *(const float4*)(S.adst + (size_t)d * 4);
    float p0 = 0.f, p1 = 0.f, p2 = 0.f, p3 = 0.f;
    for (int i = lane; i < kTot; i += 64) {
        int s = (i < k) ? (int)S.srt[base + i] : d;
        float4 as = *(const float4*)(S.asrc + (size_t)s * 4);
        float v0 = ad.x + as.x, v1 = ad.y + as.y, v2 = ad.z + as.z, v3 = ad.w + as.w;
        v0 = v0 > 0.f ? v0 : NEG * v0;
        v1 = v1 > 0.f ? v1 : NEG * v1;
        v2 = v2 > 0.f ? v2 : NEG * v2;
        v3 = v3 > 0.f ? v3 : NEG * v3;
        float e0 = __expf(v0), e1 = __expf(v1), e2 = __expf(v2), e3 = __expf(v3);
        if (i < CAP) { exSh[slot][i] = make_float4(e0, e1, e2, e3); sSh[slot][i] = s; }
        p0 += e0; p1 += e1; p2 += e2; p3 += e3;
    }
#pragma unroll
    for (int off = 32; off; off >>= 1) {
        p0 += __shfl_xor(p0, off); p1 += __shfl_xor(p1, off);
        p2 += __shfl_xor(p2, off); p3 += __shfl_xor(p3, off);
    }
    // hoisted: 4 divides per wave (wave-uniform), scale folded in
    float scale = 0.25f * (S.pw ? S.pw[S.pwi] : 1.0f);
    float i0 = scale / (p0 + 1e-16f);
    float i1 = scale / (p1 + 1e-16f);
    float i2 = scale / (p2 + 1e-16f);
    float i3 = scale / (p3 + 1e-16f);

    // per-segment normalized weights into LDS (covers min(kTot, CAP))
    int kW = kTot < CAP ? kTot : CAP;
    for (int i = lane; i < kW; i += 64) {
        float4 ex = exSh[slot][i];
        wSh[slot][i] = ex.x * i0 + ex.y * i1 + ex.z * i2 + ex.w * i3;
    }
    if (kTot <= CAP) {
        int nPad = (kTot + 7) & ~7;
        for (int i = kTot + lane; i < nPad; i += 64) { wSh[slot][i] = 0.f; sSh[slot][i] = 0; }
    }
    __syncthreads();   // unconditional: all 4 waves

    if (kTot <= CAP) {
        // main path: 8 edges/iter/wave (2 independent loads per lane)
        int g = lane >> 4, c8 = lane & 15;
        float a[8];
#pragma unroll
        for (int i = 0; i < 8; i++) a[i] = 0.f;
        int nIter = (kTot + 7) >> 3;
        for (int it = 0; it < nIter; ++it) {
            int j0 = it * 8 + g;
            int j1 = j0 + 4;
            float w0 = wSh[slot][j0], w1 = wSh[slot][j1];
            int s0 = sSh[slot][j0], s1 = sSh[slot][j1];
            ushort8 v0 = *(const ushort8*)(S.feats + (size_t)s0 * 128 + c8 * 8);
            ushort8 v1 = *(const ushort8*)(S.feats + (size_t)s1 * 128 + c8 * 8);
#pragma unroll
            for (int i = 0; i < 8; i++) {
                a[i] += w0 * __uint_as_float((unsigned)(unsigned short)v0[i] << 16);
                a[i] += w1 * __uint_as_float((unsigned)(unsigned short)v1[i] << 16);
            }
        }
#pragma unroll
        for (int i = 0; i < 8; i++) {
            a[i] += __shfl_xor(a[i], 16);
            a[i] += __shfl_xor(a[i], 32);
        }
        if (lane < 16) {
#pragma unroll
            for (int i = 0; i < 8; i++) cmb[slot][lane * 8 + i] = a[i];
        }
    } else {
        // rare fallback: degree > CAP, serial over edges within the wave
        float a0 = 0.f, a1 = 0.f;
        for (int j = 0; j < kTot; ++j) {
            float wgt; int s;
            if (j < CAP) { wgt = wSh[slot][j]; s = sSh[slot][j]; }
            else {
                s = (j < k) ? (int)S.srt[base + j] : d;
                float4 as = *(const float4*)(S.asrc + (size_t)s * 4);
                float v0 = ad.x + as.x, v1 = ad.y + as.y, v2 = ad.z + as.z, v3 = ad.w + as.w;
                v0 = v0 > 0.f ? v0 : NEG * v0;
                v1 = v1 > 0.f ? v1 : NEG * v1;
                v2 = v2 > 0.f ? v2 : NEG * v2;
                v3 = v3 > 0.f ? v3 : NEG * v3;
                wgt = __expf(v0) * i0 + __expf(v1) * i1 + __expf(v2) * i2 + __expf(v3) * i3;
            }
            unsigned v = *(const unsigned*)(S.feats + (size_t)s * 128 + 2 * lane);
            a0 += wgt * __uint_as_float(v << 16);
            a1 += wgt * __uint_as_float(v & 0xffff0000u);
        }
        cmb[slot][2 * lane] = a0;
        cmb[slot][2 * lane + 1] = a1;
    }
    __syncthreads();

    // combine pair, single acc access per dst
    {
        int dh2 = t >> 7;             // 0/1: which dst
        int c = t & 127;
        int dd = blockIdx.x * 2 + dh2;
        float sum = cmb[dh2 * 2][c] + cmb[dh2 * 2 + 1][c];
        size_t idx = (size_t)dd * 128 + c;
        if (mode) acc[idx] = bias0[c] + bias1[c] + sum;
        else      acc[idx] += sum;
    }
}

extern "C" void kernel_launch(void* const* d_in, const int* in_sizes, int n_in,
                              void* d_out, int out_size, void* d_ws, size_t ws_size,
                              hipStream_t stream)
{
    const float* x_var   = (const float*)d_in[0];
    const float* x_cls   = (const float*)d_in[1];
    const int*   mp_var  = (const int*)d_in[2];
    const int*   mp_cls  = (const int*)d_in[3];
    const int*   adj_pos = (const int*)d_in[4];
    const int*   adj_neg = (const int*)d_in[5];
    const float* W_var_emb = (const float*)d_in[6];
    const float* W_cls_emb = (const float*)d_in[7];
    const float* ln_var_g = (const float*)d_in[8];
    const float* ln_var_b = (const float*)d_in[9];
    const float* ln_cls_g = (const float*)d_in[10];
    const float* ln_cls_b = (const float*)d_in[11];
    const float* var_pw = (const float*)d_in[12];
    const float* cls_pw = (const float*)d_in[13];
    const float* sv_W  = (const float*)d_in[14];
    const float* sv_al = (const float*)d_in[15];
    const float* sv_ar = (const float*)d_in[16];
    const float* sv_b  = (const float*)d_in[17];
    const float* sc_W  = (const float*)d_in[18];
    const float* sc_al = (const float*)d_in[19];
    const float* sc_ar = (const float*)d_in[20];
    const float* sc_b  = (const float*)d_in[21];
    const float* cp_Wl = (const float*)d_in[22];
    const float* cp_Wr = (const float*)d_in[23];
    const float* cp_al = (const float*)d_in[24];
    const float* cp_ar = (const float*)d_in[25];
    const float* cp_b  = (const float*)d_in[26];
    const float* cn_Wl = (const float*)d_in[27];
    const float* cn_Wr = (const float*)d_in[28];
    const float* cn_al = (const float*)d_in[29];
    const float* cn_ar = (const float*)d_in[30];
    const float* cn_b  = (const float*)d_in[31];

    float* out0 = (float*)d_out;
    float* out1 = out0 + (size_t)NN * 128;

    float* ws = (float*)d_ws;
    size_t off = 0;
    auto alloc = [&](size_t n) { float* p = ws + off; off += n; return p; };
    float* Wt   = alloc(16384);
    float* Mbuf = alloc(8 * 1024);
    float* F   = alloc((size_t)NN * 128);
    float* G   = alloc((size_t)NN * 128);
    float* C   = alloc((size_t)NN * 128);   // hv; reused as 2x bf16 feats after self-proj
    float* D   = alloc((size_t)NN * 128);   // hc
    unsigned short* B1 = (unsigned short*)alloc((size_t)NN * 64);  // bf16 [NN][128]
    unsigned short* B2 = (unsigned short*)alloc((size_t)NN * 64);
    float* dl   = alloc(NN * 4);
    float* dr   = alloc(NN * 4);
    float* dl2  = alloc(NN * 4);
    float* dr2  = alloc(NN * 4);
    float* dl3  = alloc(NN * 4);
    float* dr3  = alloc(NN * 4);
    float* dl4  = alloc(NN * 4);
    float* dr4  = alloc(NN * 4);
    int* counts8 = (int*)alloc(8 * NN);
    int* starts8 = (int*)alloc(8 * NN);
    int* bcnt    = (int*)alloc(8 * NBKT);
    int* bstart  = (int*)alloc(8 * (NBKT + 1));
    int* bcur    = (int*)alloc(8 * NBKT);
    unsigned* recs = (unsigned*)alloc((size_t)8 * EE);
    unsigned short* sortedU = (unsigned short*)alloc((size_t)4 * EE);

    // carve two bf16 feats buffers out of C (dead after self projections)
    unsigned short* Pc = (unsigned short*)C;                       // [NN][128] bf16
    unsigned short* Pd = (unsigned short*)C + (size_t)NN * 128;    // [NN][128] bf16

    const float* WtEv = Wt;
    const float* WtEc = Wt + 8192;

    Ptr8 srcP, dstP;
    srcP.p[0] = mp_var;            dstP.p[0] = mp_var + EE;
    srcP.p[1] = mp_var + 2 * EE;   dstP.p[1] = mp_var + 3 * EE;
    srcP.p[2] = mp_cls;            dstP.p[2] = mp_cls + EE;
    srcP.p[3] = mp_cls + 2 * EE;   dstP.p[3] = mp_cls + 3 * EE;
    srcP.p[4] = adj_pos;           dstP.p[4] = adj_pos + EE;
    srcP.p[5] = adj_pos + EE;      dstP.p[5] = adj_pos;
    srcP.p[6] = adj_neg;           dstP.p[6] = adj_neg + EE;
    srcP.p[7] = adj_neg + EE;      dstP.p[7] = adj_neg;

    MArgs ma;
    ma.w[0] = sv_W;           ma.al[0] = sv_al;        ma.ar[0] = sv_ar;
    ma.w[1] = sv_W + 16384;   ma.al[1] = sv_al + 512;  ma.ar[1] = sv_ar + 512;
    ma.w[2] = sc_W;           ma.al[2] = sc_al;        ma.ar[2] = sc_ar;
    ma.w[3] = sc_W + 16384;   ma.al[3] = sc_al + 512;  ma.ar[3] = sc_ar + 512;
    ma.w[4] = cp_Wl;          ma.al[4] = cp_al;        ma.ar[4] = cp_ar;
    ma.w[5] = cp_Wr;          ma.al[5] = cp_al;        ma.ar[5] = cp_ar;
    ma.w[6] = cn_Wl;          ma.al[6] = cn_al;        ma.ar[6] = cn_ar;
    ma.w[7] = cn_Wr;          ma.al[7] = cn_al;        ma.ar[7] = cn_ar;

    // ---- two-level bucket sort of all 8 edge lists ----
    zero_bcnt<<<(8 * NBKT + 255) / 256, 256, 0, stream>>>(bcnt);
    bucket_count<<<8 * PA_B, 256, 0, stream>>>(dstP, bcnt);
    bucket_scan<<<8, 256, 0, stream>>>(bcnt, bstart, bcur);
    bucket_place<<<8 * PA_B, 256, 0, stream>>>(srcP, dstP, bcur, recs);
    bucket_final<<<8 * NBKT, 256, 0, stream>>>(recs, bstart, starts8, counts8, sortedU);

    transpose_emb<<<64, 256, 0, stream>>>(W_var_emb, W_cls_emb, Wt);
    make_M<<<8, 256, 0, stream>>>(ma, Mbuf);
    embed_ln<<<NN / 8, 128, 0, stream>>>(x_var, WtEv, ln_var_g, ln_var_b, var_pw, sv_b, F, C);
    embed_ln<<<NN / 8, 128, 0, stream>>>(x_cls, WtEc, ln_cls_g, ln_cls_b, cls_pw, sc_b, G, D);

    const int PB = (NN + 63) / 64;

    // ---- self attention: fused pair projection + fused pair agg per side ----
    for (int side = 0; side < 2; ++side) {
        const float* h    = side ? D : C;
        float*       accp = side ? G : F;
        const float* pw   = side ? cls_pw : var_pw;
        int s0 = side * 2, s1 = side * 2 + 1;
        mfma_proj2<<<PB, 256, 0, stream>>>(h, ma.w[s0], ma.w[s1],
                                           Mbuf + s0 * 1024, Mbuf + s1 * 1024,
                                           B1, B2,
                                           (float4*)dl, (float4*)dr,
                                           (float4*)dl2, (float4*)dr2);
        SegArg SA, SB;
        SA.starts = starts8 + s0 * NN; SA.counts = counts8 + s0 * NN;
        SA.srt = sortedU + (size_t)s0 * EE;
        SA.adst = dl;  SA.asrc = dr;  SA.feats = B1; SA.pw = pw; SA.pwi = 0; SA.hasLoop = 1;
        SB.starts = starts8 + s1 * NN; SB.counts = counts8 + s1 * NN;
        SB.srt = sortedU + (size_t)s1 * EE;
        SB.adst = dl2; SB.asrc = dr2; SB.feats = B2; SB.pw = pw; SB.pwi = 1; SB.hasLoop = 1;
        agg_fused<<<NN / 2, 256, 0, stream>>>(SA, SB, cp_b, cn_b, accp, 0);
    }

    // ---- cross attention: pair projections by shared input, fuse pos/neg agg ----
    mfma_proj2<<<PB, 256, 0, stream>>>(F, ma.w[4], ma.w[6],
                                       Mbuf + 4 * 1024, Mbuf + 6 * 1024,
                                       B1, Pc,
                                       (float4*)dl, (float4*)dr,     // pos: al, ar_
                                       (float4*)dl3, (float4*)dr3);  // neg: al, ar_
    mfma_proj2<<<PB, 256, 0, stream>>>(G, ma.w[5], ma.w[7],
                                       Mbuf + 5 * 1024, Mbuf + 7 * 1024,
                                       B2, Pd,
                                       (float4*)dl2, (float4*)dr2,   // pos: al_, ar
                                       (float4*)dl4, (float4*)dr4);  // neg: al_, ar

    {   // out0 (var nodes): seg4 (pos) + seg6 (neg), bias written in-kernel
        SegArg SA, SB;
        SA.starts = starts8 + 4 * NN; SA.counts = counts8 + 4 * NN;
        SA.srt = sortedU + (size_t)4 * EE;
        SA.adst = dl;  SA.asrc = dr2; SA.feats = B2; SA.pw = nullptr; SA.pwi = 0; SA.hasLoop = 0;
        SB.starts = starts8 + 6 * NN; SB.counts = counts8 + 6 * NN;
        SB.srt = sortedU + (size_t)6 * EE;
        SB.adst = dl3; SB.asrc = dr4; SB.feats = Pd; SB.pw = nullptr; SB.pwi = 0; SB.hasLoop = 0;
        agg_fused<<<NN / 2, 256, 0, stream>>>(SA, SB, cp_b, cn_b, out0, 1);
    }
    {   // out1 (cls nodes): seg5 (pos) + seg7 (neg)
        SegArg SA, SB;
        SA.starts = starts8 + 5 * NN; SA.counts = counts8 + 5 * NN;
        SA.srt = sortedU + (size_t)5 * EE;
        SA.adst = dl2; SA.asrc = dr;  SA.feats = B1; SA.pw = nullptr; SA.pwi = 0; SA.hasLoop = 0;
        SB.starts = starts8 + 7 * NN; SB.counts = counts8 + 7 * NN;
        SB.srt = sortedU + (size_t)7 * EE;
        SB.adst = dl4; SB.asrc = dr3; SB.feats = Pc; SB.pw = nullptr; SB.pwi = 0; SB.hasLoop = 0;
        agg_fused<<<NN / 2, 256, 0, stream>>>(SA, SB, cp_b, cn_b, out1, 1);
    }
}

// Round 3
// 729.255 us; speedup vs baseline: 1.2896x; 1.0345x over previous
//
#include <hip/hip_runtime.h>
#include <hip/hip_bf16.h>

#define NN 50000
#define EE 640000
#define NEG 0.2f
#define CAP 64           // per-segment cache; degree ~ Poisson(12.8), P(k>=64) ~ 1e-24

#define BSH 9                          // 512 dsts per bucket
#define NBKT 98                        // ceil(NN/512)
#define FCAP 7168                      // LDS record stage in bucket_final
#define CHUNKA 8192
#define PA_B 79                        // ceil(EE/CHUNKA)

struct Ptr8 { const int* p[8]; };
struct MArgs { const float* w[8]; const float* al[8]; const float* ar[8]; };

struct SegArg {
    const int* starts;
    const int* counts;
    const unsigned short* srt;
    const float* adst;
    const float* asrc;
    const unsigned short* feats;
    const float* pw;
    int pwi;
    int hasLoop;
};

typedef __attribute__((ext_vector_type(8))) short short8;
typedef __attribute__((ext_vector_type(8))) unsigned short ushort8;
typedef __attribute__((ext_vector_type(4))) float floatx4;

__device__ __forceinline__ unsigned short f2bf(float x) {
    unsigned b = __float_as_uint(x);
    b = b + 0x7fffu + ((b >> 16) & 1u);   // RNE
    return (unsigned short)(b >> 16);
}

__device__ __forceinline__ float4 leakyexp4(float4 ad, float4 as) {
    float v0 = ad.x + as.x, v1 = ad.y + as.y, v2 = ad.z + as.z, v3 = ad.w + as.w;
    v0 = v0 > 0.f ? v0 : NEG * v0;
    v1 = v1 > 0.f ? v1 : NEG * v1;
    v2 = v2 > 0.f ? v2 : NEG * v2;
    v3 = v3 > 0.f ? v3 : NEG * v3;
    return make_float4(__expf(v0), __expf(v1), __expf(v2), __expf(v3));
}

// ---------------- transpose embedding weights ----------------
__global__ void transpose_emb(const float* __restrict__ wev, const float* __restrict__ wec,
                              float* __restrict__ out)
{
    int i = blockIdx.x * 256 + threadIdx.x;
    if (i < 8192) { out[i] = wev[(i & 127) * 64 + (i >> 7)]; return; }
    if (i < 16384) { int j = i - 8192; out[i] = wec[(j & 127) * 64 + (j >> 7)]; }
}

// ---------------- M[p] = W_p^T @ [attL | attR]  (128x8 per projection) ----------------
__global__ void make_M(MArgs a, float* __restrict__ Mbuf)
{
    int b = blockIdx.x;
    const float* W  = a.w[b];
    const float* AL = a.al[b];
    const float* AR = a.ar[b];
    for (int e = threadIdx.x; e < 1024; e += 256) {
        int k = e >> 3, h = e & 7;
        const float* att = (h < 4) ? AL : AR;
        int hh = h & 3;
        float s = 0.f;
        for (int c = 0; c < 128; c++) s += W[c * 128 + k] * att[c * 4 + hh];
        Mbuf[b * 1024 + e] = s;
    }
}

// ---------------- embedding GEMM + LayerNorm ----------------
__global__ void embed_ln(const float* __restrict__ x, const float* __restrict__ Wt,
                         const float* __restrict__ g, const float* __restrict__ b,
                         const float* __restrict__ pw, const float* __restrict__ sb,
                         float* __restrict__ F, float* __restrict__ C)
{
    __shared__ float lx[8][64];
    __shared__ float red[2][8][2];
    int c = threadIdx.x;
    int n0 = blockIdx.x * 8;
    for (int t = c; t < 8 * 64; t += 128) {
        lx[t >> 6][t & 63] = x[(size_t)(n0 + (t >> 6)) * 64 + (t & 63)];
    }
    __syncthreads();
    float acc[8];
#pragma unroll
    for (int m = 0; m < 8; m++) acc[m] = 0.f;
    for (int k = 0; k < 64; k++) {
        float w = Wt[k * 128 + c];
#pragma unroll
        for (int m = 0; m < 8; m++) acc[m] += lx[m][k] * w;
    }
    int lane = c & 63, wv = c >> 6;
#pragma unroll
    for (int m = 0; m < 8; m++) {
        float s1 = acc[m], s2 = acc[m] * acc[m];
        for (int off = 32; off; off >>= 1) { s1 += __shfl_xor(s1, off); s2 += __shfl_xor(s2, off); }
        if (lane == 0) { red[wv][m][0] = s1; red[wv][m][1] = s2; }
    }
    __syncthreads();
    float biassum = pw[0] * sb[c] + pw[1] * sb[128 + c];
    float gg = g[c], bb = b[c];
#pragma unroll
    for (int m = 0; m < 8; m++) {
        float s1 = red[0][m][0] + red[1][m][0];
        float s2 = red[0][m][1] + red[1][m][1];
        float mu  = s1 * (1.f / 128.f);
        float var = s2 * (1.f / 128.f) - mu * mu;
        float inv = rsqrtf(var + 1e-5f);
        float v = acc[m];
        size_t idx = (size_t)(n0 + m) * 128 + c;
        F[idx] = v + biassum;
        C[idx] = (v - mu) * inv * gg + bb;
    }
}

// ---------------- fused pair projection ----------------
__device__ __forceinline__ void stage_W(const float* __restrict__ W,
                                        unsigned short* __restrict__ WL, int t)
{
    for (int i = t; i < 2048; i += 256) {
        int n = i >> 4, c16 = i & 15;
        const float* src = W + n * 128 + c16 * 8;
        short8 v;
#pragma unroll
        for (int j = 0; j < 8; j++) v[j] = (short)f2bf(src[j]);
        *(short8*)&WL[(n * 16 + (c16 ^ (n & 15))) * 8] = v;
    }
}

__global__ __launch_bounds__(256) void mfma_proj2(
    const float* __restrict__ in,        // [NN][128] fp32
    const float* __restrict__ W0, const float* __restrict__ W1,
    const float* __restrict__ M0, const float* __restrict__ M1,
    unsigned short* __restrict__ ob0, unsigned short* __restrict__ ob1,
    float4* __restrict__ dl0, float4* __restrict__ dr0,
    float4* __restrict__ dl1, float4* __restrict__ dr1)
{
    __shared__ unsigned short WL[16384];  // 128 rows x 16 chunks x 8 bf16, swizzled
    __shared__ float ML[2048];            // 2 x 128 x 8

    int t = threadIdx.x;
    stage_W(W0, WL, t);
    for (int i = t; i < 1024; i += 256) { ML[i] = M0[i]; ML[1024 + i] = M1[i]; }
    __syncthreads();

    int w = t >> 6, lane = t & 63;
    int ln = lane & 15, quad = lane >> 4;
    int rbase = blockIdx.x * 64 + w * 16;
    int row = rbase + ln;
    int arow = (row < NN) ? row : (NN - 1);

    short8 afrag[4];
    float p[16];
#pragma unroll
    for (int h = 0; h < 16; h++) p[h] = 0.f;
#pragma unroll
    for (int kc = 0; kc < 4; kc++) {
        int k0 = kc * 32 + quad * 8;
        const float* ap = in + (size_t)arow * 128 + k0;
        float av[8];
#pragma unroll
        for (int j = 0; j < 8; j++) av[j] = ap[j];
#pragma unroll
        for (int j = 0; j < 8; j++) {
            afrag[kc][j] = (short)f2bf(av[j]);
            const float* m0 = &ML[(k0 + j) * 8];
            const float* m1 = &ML[1024 + (k0 + j) * 8];
#pragma unroll
            for (int h = 0; h < 8; h++) { p[h] += av[j] * m0[h]; p[8 + h] += av[j] * m1[h]; }
        }
    }
#pragma unroll
    for (int h = 0; h < 16; h++) {
        p[h] += __shfl_xor(p[h], 16);
        p[h] += __shfl_xor(p[h], 32);
    }
    if (quad == 0 && row < NN) {
        dl0[row] = make_float4(p[0], p[1], p[2], p[3]);
        dr0[row] = make_float4(p[4], p[5], p[6], p[7]);
        dl1[row] = make_float4(p[8], p[9], p[10], p[11]);
        dr1[row] = make_float4(p[12], p[13], p[14], p[15]);
    }

    // ---- phase 0: MFMA with W0 ----
#pragma unroll
    for (int ct = 0; ct < 8; ct++) {
        floatx4 acc = {0.f, 0.f, 0.f, 0.f};
#pragma unroll
        for (int kc = 0; kc < 4; kc++) {
            int c16 = kc * 4 + quad;
            int n = ct * 16 + ln;
            short8 bfr = *(const short8*)&WL[(n * 16 + (c16 ^ ln)) * 8];
            acc = __builtin_amdgcn_mfma_f32_16x16x32_bf16(afrag[kc], bfr, acc, 0, 0, 0);
        }
#pragma unroll
        for (int r = 0; r < 4; r++) {
            int rr = rbase + quad * 4 + r;
            if (rr < NN) ob0[(size_t)rr * 128 + ct * 16 + ln] = f2bf(acc[r]);
        }
    }
    __syncthreads();
    stage_W(W1, WL, t);
    __syncthreads();
    // ---- phase 1: MFMA with W1 ----
#pragma unroll
    for (int ct = 0; ct < 8; ct++) {
        floatx4 acc = {0.f, 0.f, 0.f, 0.f};
#pragma unroll
        for (int kc = 0; kc < 4; kc++) {
            int c16 = kc * 4 + quad;
            int n = ct * 16 + ln;
            short8 bfr = *(const short8*)&WL[(n * 16 + (c16 ^ ln)) * 8];
            acc = __builtin_amdgcn_mfma_f32_16x16x32_bf16(afrag[kc], bfr, acc, 0, 0, 0);
        }
#pragma unroll
        for (int r = 0; r < 4; r++) {
            int rr = rbase + quad * 4 + r;
            if (rr < NN) ob1[(size_t)rr * 128 + ct * 16 + ln] = f2bf(acc[r]);
        }
    }
}

// ================= two-level bucket sort (8 edge lists) =================
__global__ void zero_bcnt(int* __restrict__ p)
{
    int i = blockIdx.x * 256 + threadIdx.x;
    if (i < 8 * NBKT) p[i] = 0;
}

__global__ void bucket_count(Ptr8 dst, int* __restrict__ bcnt)
{
    __shared__ int h[NBKT];
    int l = blockIdx.x / PA_B, cb = blockIdx.x % PA_B;
    const int* dp = dst.p[l];
    for (int i = threadIdx.x; i < NBKT; i += 256) h[i] = 0;
    __syncthreads();
    int e0 = cb * CHUNKA;
    for (int i = threadIdx.x; i < CHUNKA; i += 256) {
        int e = e0 + i;
        if (e < EE) atomicAdd(&h[dp[e] >> BSH], 1);
    }
    __syncthreads();
    for (int i = threadIdx.x; i < NBKT; i += 256)
        if (h[i]) atomicAdd(&bcnt[l * NBKT + i], h[i]);
}

__global__ void bucket_scan(const int* __restrict__ bcnt, int* __restrict__ bstart,
                            int* __restrict__ bcur)
{
    __shared__ int sh[NBKT];
    int l = blockIdx.x;
    for (int i = threadIdx.x; i < NBKT; i += 256) sh[i] = bcnt[l * NBKT + i];
    __syncthreads();
    if (threadIdx.x == 0) {
        int acc = 0;
        for (int i = 0; i < NBKT; i++) { int t = sh[i]; sh[i] = acc; acc += t; }
    }
    __syncthreads();
    for (int i = threadIdx.x; i < NBKT; i += 256) {
        bstart[l * (NBKT + 1) + i] = sh[i];
        bcur[l * NBKT + i] = sh[i];
    }
    if (threadIdx.x == 0) bstart[l * (NBKT + 1) + NBKT] = EE;
}

__global__ void bucket_place(Ptr8 src, Ptr8 dst, int* __restrict__ bcur,
                             unsigned* __restrict__ recs)
{
    __shared__ int h[NBKT];
    __shared__ int base[NBKT];
    int l = blockIdx.x / PA_B, cb = blockIdx.x % PA_B;
    const int* sp = src.p[l];
    const int* dp = dst.p[l];
    for (int i = threadIdx.x; i < NBKT; i += 256) h[i] = 0;
    __syncthreads();
    int e0 = cb * CHUNKA;
    for (int i = threadIdx.x; i < CHUNKA; i += 256) {
        int e = e0 + i;
        if (e < EE) atomicAdd(&h[dp[e] >> BSH], 1);
    }
    __syncthreads();
    for (int i = threadIdx.x; i < NBKT; i += 256) {
        int c = h[i];
        base[i] = c ? atomicAdd(&bcur[l * NBKT + i], c) : 0;
        h[i] = 0;
    }
    __syncthreads();
    unsigned* rl = recs + (size_t)l * EE;
    for (int i = threadIdx.x; i < CHUNKA; i += 256) {
        int e = e0 + i;
        if (e >= EE) continue;
        int d = dp[e];
        int b = d >> BSH;
        int pos = base[b] + atomicAdd(&h[b], 1);
        rl[pos] = ((unsigned)sp[e] << 16) | (unsigned)d;
    }
}

// one block per 512-dst bucket: stage recs in LDS, parallel scan, exact placement
__global__ __launch_bounds__(256) void bucket_final(
    const unsigned* __restrict__ recs, const int* __restrict__ bstart,
    int* __restrict__ starts8, int* __restrict__ counts8,
    unsigned short* __restrict__ sortedU)
{
    __shared__ unsigned R[FCAP];
    __shared__ int cnt[512];
    __shared__ int cur[512];
    __shared__ int psum[256];
    int l = blockIdx.x / NBKT, b = blockIdx.x % NBKT;
    int d0 = b << BSH;
    int nd = min(512, NN - d0);
    int ebase = bstart[l * (NBKT + 1) + b];
    int ecnt  = bstart[l * (NBKT + 1) + b + 1] - ebase;
    const unsigned* rp = recs + (size_t)l * EE + ebase;
    int t = threadIdx.x;
    bool inLds = (ecnt <= FCAP);

    for (int i = t; i < 512; i += 256) cnt[i] = 0;
    __syncthreads();
    for (int i = t; i < ecnt; i += 256) {
        unsigned r = rp[i];
        if (inLds) R[i] = r;
        atomicAdd(&cnt[(r & 0xffffu) - d0], 1);
    }
    __syncthreads();
    // exclusive scan of cnt[512]: pairwise partials + 256-ladder
    int s0 = cnt[2 * t] + cnt[2 * t + 1];
    psum[t] = s0;
    __syncthreads();
    for (int off = 1; off < 256; off <<= 1) {
        int x = (t >= off) ? psum[t - off] : 0;
        __syncthreads();
        psum[t] += x;
        __syncthreads();
    }
    int excl = psum[t] - s0;
    cur[2 * t] = excl;
    cur[2 * t + 1] = excl + cnt[2 * t];
    __syncthreads();
    for (int i = t; i < nd; i += 256) {
        starts8[l * NN + d0 + i] = ebase + cur[i];
        counts8[l * NN + d0 + i] = cnt[i];
    }
    __syncthreads();
    unsigned short* so = sortedU + (size_t)l * EE + ebase;
    for (int i = t; i < ecnt; i += 256) {
        unsigned r = inLds ? R[i] : rp[i];
        int dloc = (int)(r & 0xffffu) - d0;
        int pos = atomicAdd(&cur[dloc], 1);
        so[pos] = (unsigned short)(r >> 16);
    }
}

// ---------------- fused pair aggregation, 16-lane groups ----------------
// 256 threads = 16 groups of 16 lanes; group = one (dst, segment) pair.
// 8 dsts x 2 segments per block. Both segs of a dst live in the SAME wave
// (groups g and g^1) so the pair-combine is a single shfl_xor(16) and the
// kernel needs no __syncthreads. Softmax den: 4-level butterfly over 16
// lanes. Gather: each lane owns 8 fixed channels; group walks edges
// serially (w,s broadcast from LDS); no output reduction needed.
// mode 0: acc += segA+segB (self residual). mode 1: acc = bias0+bias1+segA+segB.
__global__ __launch_bounds__(256, 8) void agg_fused(
    SegArg A, SegArg B,
    const float* __restrict__ bias0, const float* __restrict__ bias1,
    float* __restrict__ acc, int mode)
{
    __shared__ float          wSh[16][CAP];   // 4 KB
    __shared__ unsigned short sSh[16][CAP];   // 2 KB

    int t = threadIdx.x;
    int gid = t >> 4;            // 0..15: group (dst-local * 2 + seg)
    int sub = t & 15;
    int seg = gid & 1;
    int d   = blockIdx.x * 8 + (gid >> 1);

    const int* starts = seg ? B.starts : A.starts;
    const int* counts = seg ? B.counts : A.counts;
    const unsigned short* srt = seg ? B.srt : A.srt;
    const float* adst = seg ? B.adst : A.adst;
    const float* asrc = seg ? B.asrc : A.asrc;
    const unsigned short* feats = seg ? B.feats : A.feats;
    const float* pw = seg ? B.pw : A.pw;
    int pwi = seg ? B.pwi : A.pwi;
    int hasLoop = seg ? B.hasLoop : A.hasLoop;

    int base = starts[d];
    int k = counts[d];
    int kTot = k + hasLoop;

    float4 ad = *(const float4*)(adst + (size_t)d * 4);

    // pass 1: denominators (and cache src ids)
    float p0 = 0.f, p1 = 0.f, p2 = 0.f, p3 = 0.f;
    for (int i = sub; i < kTot; i += 16) {
        int s = (i < k) ? (int)srt[base + i] : d;
        if (i < CAP) sSh[gid][i] = (unsigned short)s;
        float4 as = *(const float4*)(asrc + (size_t)s * 4);
        float4 e = leakyexp4(ad, as);
        p0 += e.x; p1 += e.y; p2 += e.z; p3 += e.w;
    }
#pragma unroll
    for (int off = 1; off <= 8; off <<= 1) {
        p0 += __shfl_xor(p0, off); p1 += __shfl_xor(p1, off);
        p2 += __shfl_xor(p2, off); p3 += __shfl_xor(p3, off);
    }
    float scale = 0.25f * (pw ? pw[pwi] : 1.0f);
    float i0 = scale / (p0 + 1e-16f);
    float i1 = scale / (p1 + 1e-16f);
    float i2 = scale / (p2 + 1e-16f);
    float i3 = scale / (p3 + 1e-16f);

    // pass 2a: per-edge weights (recompute exp; asrc is L2-hot, 800 KB total)
    int kW = kTot < CAP ? kTot : CAP;
    for (int i = sub; i < kW; i += 16) {
        int s = (int)sSh[gid][i];          // same-lane readback
        float4 as = *(const float4*)(asrc + (size_t)s * 4);
        float4 e = leakyexp4(ad, as);
        wSh[gid][i] = e.x * i0 + e.y * i1 + e.z * i2 + e.w * i3;
    }
    // producer/consumer in the same wave: lgkmcnt ordering suffices, no barrier

    // gather: lane owns channels sub*8 .. sub*8+7
    float a[8];
#pragma unroll
    for (int i = 0; i < 8; i++) a[i] = 0.f;
    const unsigned short* fbase = feats + sub * 8;
    for (int j = 0; j < kW; ++j) {
        float wgt = wSh[gid][j];           // broadcast within group
        int s = (int)sSh[gid][j];
        ushort8 v = *(const ushort8*)(fbase + (size_t)s * 128);
#pragma unroll
        for (int i = 0; i < 8; i++)
            a[i] += wgt * __uint_as_float((unsigned)(unsigned short)v[i] << 16);
    }
    for (int j = CAP; j < kTot; ++j) {     // essentially-never fallback
        int s = (j < k) ? (int)srt[base + j] : d;
        float4 as = *(const float4*)(asrc + (size_t)s * 4);
        float4 e = leakyexp4(ad, as);
        float wgt = e.x * i0 + e.y * i1 + e.z * i2 + e.w * i3;
        ushort8 v = *(const ushort8*)(fbase + (size_t)s * 128);
#pragma unroll
        for (int i = 0; i < 8; i++)
            a[i] += wgt * __uint_as_float((unsigned)(unsigned short)v[i] << 16);
    }

    // combine the two segments of this dst (groups g <-> g^1, lanes xor 16)
#pragma unroll
    for (int i = 0; i < 8; i++) a[i] += __shfl_xor(a[i], 16);

    if (seg == 0) {
        size_t idx = (size_t)d * 128 + sub * 8;
        float4* ap = (float4*)(acc + idx);
        float4 lo = make_float4(a[0], a[1], a[2], a[3]);
        float4 hi = make_float4(a[4], a[5], a[6], a[7]);
        if (mode) {
            const float4* b0 = (const float4*)(bias0 + sub * 8);
            const float4* b1 = (const float4*)(bias1 + sub * 8);
            float4 c0 = b0[0], c1 = b0[1], d0v = b1[0], d1v = b1[1];
            ap[0] = make_float4(c0.x + d0v.x + lo.x, c0.y + d0v.y + lo.y,
                                c0.z + d0v.z + lo.z, c0.w + d0v.w + lo.w);
            ap[1] = make_float4(c1.x + d1v.x + hi.x, c1.y + d1v.y + hi.y,
                                c1.z + d1v.z + hi.z, c1.w + d1v.w + hi.w);
        } else {
            float4 r0 = ap[0], r1 = ap[1];
            ap[0] = make_float4(r0.x + lo.x, r0.y + lo.y, r0.z + lo.z, r0.w + lo.w);
            ap[1] = make_float4(r1.x + hi.x, r1.y + hi.y, r1.z + hi.z, r1.w + hi.w);
        }
    }
}

extern "C" void kernel_launch(void* const* d_in, const int* in_sizes, int n_in,
                              void* d_out, int out_size, void* d_ws, size_t ws_size,
                              hipStream_t stream)
{
    const float* x_var   = (const float*)d_in[0];
    const float* x_cls   = (const float*)d_in[1];
    const int*   mp_var  = (const int*)d_in[2];
    const int*   mp_cls  = (const int*)d_in[3];
    const int*   adj_pos = (const int*)d_in[4];
    const int*   adj_neg = (const int*)d_in[5];
    const float* W_var_emb = (const float*)d_in[6];
    const float* W_cls_emb = (const float*)d_in[7];
    const float* ln_var_g = (const float*)d_in[8];
    const float* ln_var_b = (const float*)d_in[9];
    const float* ln_cls_g = (const float*)d_in[10];
    const float* ln_cls_b = (const float*)d_in[11];
    const float* var_pw = (const float*)d_in[12];
    const float* cls_pw = (const float*)d_in[13];
    const float* sv_W  = (const float*)d_in[14];
    const float* sv_al = (const float*)d_in[15];
    const float* sv_ar = (const float*)d_in[16];
    const float* sv_b  = (const float*)d_in[17];
    const float* sc_W  = (const float*)d_in[18];
    const float* sc_al = (const float*)d_in[19];
    const float* sc_ar = (const float*)d_in[20];
    const float* sc_b  = (const float*)d_in[21];
    const float* cp_Wl = (const float*)d_in[22];
    const float* cp_Wr = (const float*)d_in[23];
    const float* cp_al = (const float*)d_in[24];
    const float* cp_ar = (const float*)d_in[25];
    const float* cp_b  = (const float*)d_in[26];
    const float* cn_Wl = (const float*)d_in[27];
    const float* cn_Wr = (const float*)d_in[28];
    const float* cn_al = (const float*)d_in[29];
    const float* cn_ar = (const float*)d_in[30];
    const float* cn_b  = (const float*)d_in[31];

    float* out0 = (float*)d_out;
    float* out1 = out0 + (size_t)NN * 128;

    float* ws = (float*)d_ws;
    size_t off = 0;
    auto alloc = [&](size_t n) { float* p = ws + off; off += n; return p; };
    float* Wt   = alloc(16384);
    float* Mbuf = alloc(8 * 1024);
    float* F   = alloc((size_t)NN * 128);
    float* G   = alloc((size_t)NN * 128);
    float* C   = alloc((size_t)NN * 128);   // hv; reused as 2x bf16 feats after self-proj
    float* D   = alloc((size_t)NN * 128);   // hc
    unsigned short* B1 = (unsigned short*)alloc((size_t)NN * 64);  // bf16 [NN][128]
    unsigned short* B2 = (unsigned short*)alloc((size_t)NN * 64);
    float* dl   = alloc(NN * 4);
    float* dr   = alloc(NN * 4);
    float* dl2  = alloc(NN * 4);
    float* dr2  = alloc(NN * 4);
    float* dl3  = alloc(NN * 4);
    float* dr3  = alloc(NN * 4);
    float* dl4  = alloc(NN * 4);
    float* dr4  = alloc(NN * 4);
    int* counts8 = (int*)alloc(8 * NN);
    int* starts8 = (int*)alloc(8 * NN);
    int* bcnt    = (int*)alloc(8 * NBKT);
    int* bstart  = (int*)alloc(8 * (NBKT + 1));
    int* bcur    = (int*)alloc(8 * NBKT);
    unsigned* recs = (unsigned*)alloc((size_t)8 * EE);
    unsigned short* sortedU = (unsigned short*)alloc((size_t)4 * EE);

    // carve two bf16 feats buffers out of C (dead after self projections)
    unsigned short* Pc = (unsigned short*)C;                       // [NN][128] bf16
    unsigned short* Pd = (unsigned short*)C + (size_t)NN * 128;    // [NN][128] bf16

    const float* WtEv = Wt;
    const float* WtEc = Wt + 8192;

    Ptr8 srcP, dstP;
    srcP.p[0] = mp_var;            dstP.p[0] = mp_var + EE;
    srcP.p[1] = mp_var + 2 * EE;   dstP.p[1] = mp_var + 3 * EE;
    srcP.p[2] = mp_cls;            dstP.p[2] = mp_cls + EE;
    srcP.p[3] = mp_cls + 2 * EE;   dstP.p[3] = mp_cls + 3 * EE;
    srcP.p[4] = adj_pos;           dstP.p[4] = adj_pos + EE;
    srcP.p[5] = adj_pos + EE;      dstP.p[5] = adj_pos;
    srcP.p[6] = adj_neg;           dstP.p[6] = adj_neg + EE;
    srcP.p[7] = adj_neg + EE;      dstP.p[7] = adj_neg;

    MArgs ma;
    ma.w[0] = sv_W;           ma.al[0] = sv_al;        ma.ar[0] = sv_ar;
    ma.w[1] = sv_W + 16384;   ma.al[1] = sv_al + 512;  ma.ar[1] = sv_ar + 512;
    ma.w[2] = sc_W;           ma.al[2] = sc_al;        ma.ar[2] = sc_ar;
    ma.w[3] = sc_W + 16384;   ma.al[3] = sc_al + 512;  ma.ar[3] = sc_ar + 512;
    ma.w[4] = cp_Wl;          ma.al[4] = cp_al;        ma.ar[4] = cp_ar;
    ma.w[5] = cp_Wr;          ma.al[5] = cp_al;        ma.ar[5] = cp_ar;
    ma.w[6] = cn_Wl;          ma.al[6] = cn_al;        ma.ar[6] = cn_ar;
    ma.w[7] = cn_Wr;          ma.al[7] = cn_al;        ma.ar[7] = cn_ar;

    // ---- two-level bucket sort of all 8 edge lists ----
    zero_bcnt<<<(8 * NBKT + 255) / 256, 256, 0, stream>>>(bcnt);
    bucket_count<<<8 * PA_B, 256, 0, stream>>>(dstP, bcnt);
    bucket_scan<<<8, 256, 0, stream>>>(bcnt, bstart, bcur);
    bucket_place<<<8 * PA_B, 256, 0, stream>>>(srcP, dstP, bcur, recs);
    bucket_final<<<8 * NBKT, 256, 0, stream>>>(recs, bstart, starts8, counts8, sortedU);

    transpose_emb<<<64, 256, 0, stream>>>(W_var_emb, W_cls_emb, Wt);
    make_M<<<8, 256, 0, stream>>>(ma, Mbuf);
    embed_ln<<<NN / 8, 128, 0, stream>>>(x_var, WtEv, ln_var_g, ln_var_b, var_pw, sv_b, F, C);
    embed_ln<<<NN / 8, 128, 0, stream>>>(x_cls, WtEc, ln_cls_g, ln_cls_b, cls_pw, sc_b, G, D);

    const int PB = (NN + 63) / 64;
    const int AB = NN / 8;   // 6250 blocks, 8 dsts each

    // ---- self attention: fused pair projection + fused pair agg per side ----
    for (int side = 0; side < 2; ++side) {
        const float* h    = side ? D : C;
        float*       accp = side ? G : F;
        const float* pw   = side ? cls_pw : var_pw;
        int s0 = side * 2, s1 = side * 2 + 1;
        mfma_proj2<<<PB, 256, 0, stream>>>(h, ma.w[s0], ma.w[s1],
                                           Mbuf + s0 * 1024, Mbuf + s1 * 1024,
                                           B1, B2,
                                           (float4*)dl, (float4*)dr,
                                           (float4*)dl2, (float4*)dr2);
        SegArg SA, SB;
        SA.starts = starts8 + s0 * NN; SA.counts = counts8 + s0 * NN;
        SA.srt = sortedU + (size_t)s0 * EE;
        SA.adst = dl;  SA.asrc = dr;  SA.feats = B1; SA.pw = pw; SA.pwi = 0; SA.hasLoop = 1;
        SB.starts = starts8 + s1 * NN; SB.counts = counts8 + s1 * NN;
        SB.srt = sortedU + (size_t)s1 * EE;
        SB.adst = dl2; SB.asrc = dr2; SB.feats = B2; SB.pw = pw; SB.pwi = 1; SB.hasLoop = 1;
        agg_fused<<<AB, 256, 0, stream>>>(SA, SB, cp_b, cn_b, accp, 0);
    }

    // ---- cross attention: pair projections by shared input, fuse pos/neg agg ----
    mfma_proj2<<<PB, 256, 0, stream>>>(F, ma.w[4], ma.w[6],
                                       Mbuf + 4 * 1024, Mbuf + 6 * 1024,
                                       B1, Pc,
                                       (float4*)dl, (float4*)dr,     // pos: al, ar_
                                       (float4*)dl3, (float4*)dr3);  // neg: al, ar_
    mfma_proj2<<<PB, 256, 0, stream>>>(G, ma.w[5], ma.w[7],
                                       Mbuf + 5 * 1024, Mbuf + 7 * 1024,
                                       B2, Pd,
                                       (float4*)dl2, (float4*)dr2,   // pos: al_, ar
                                       (float4*)dl4, (float4*)dr4);  // neg: al_, ar

    {   // out0 (var nodes): seg4 (pos) + seg6 (neg), bias written in-kernel
        SegArg SA, SB;
        SA.starts = starts8 + 4 * NN; SA.counts = counts8 + 4 * NN;
        SA.srt = sortedU + (size_t)4 * EE;
        SA.adst = dl;  SA.asrc = dr2; SA.feats = B2; SA.pw = nullptr; SA.pwi = 0; SA.hasLoop = 0;
        SB.starts = starts8 + 6 * NN; SB.counts = counts8 + 6 * NN;
        SB.srt = sortedU + (size_t)6 * EE;
        SB.adst = dl3; SB.asrc = dr4; SB.feats = Pd; SB.pw = nullptr; SB.pwi = 0; SB.hasLoop = 0;
        agg_fused<<<AB, 256, 0, stream>>>(SA, SB, cp_b, cn_b, out0, 1);
    }
    {   // out1 (cls nodes): seg5 (pos) + seg7 (neg)
        SegArg SA, SB;
        SA.starts = starts8 + 5 * NN; SA.counts = counts8 + 5 * NN;
        SA.srt = sortedU + (size_t)5 * EE;
        SA.adst = dl2; SA.asrc = dr;  SA.feats = B1; SA.pw = nullptr; SA.pwi = 0; SA.hasLoop = 0;
        SB.starts = starts8 + 7 * NN; SB.counts = counts8 + 7 * NN;
        SB.srt = sortedU + (size_t)7 * EE;
        SB.adst = dl4; SB.asrc = dr3; SB.feats = Pc; SB.pw = nullptr; SB.pwi = 0; SB.hasLoop = 0;
        agg_fused<<<AB, 256, 0, stream>>>(SA, SB, cp_b, cn_b, out1, 1);
    }
}

// Round 4
// 691.121 us; speedup vs baseline: 1.3608x; 1.0552x over previous
//
#include <hip/hip_runtime.h>
#include <hip/hip_bf16.h>

#define NN 50000
#define EE 640000
#define NEG 0.2f
#define CAP 64           // per-segment cache; degree ~ Poisson(12.8), P(k>=64) ~ 1e-24

#define BSH 9                          // 512 dsts per bucket
#define NBKT 98                        // ceil(NN/512)
#define FCAP 7168                      // LDS record stage in bucket_final
#define CHUNKA 8192
#define PA_B 79                        // ceil(EE/CHUNKA)

struct Ptr8 { const int* p[8]; };
struct MArgs { const float* w[8]; const float* al[8]; const float* ar[8]; };

struct SegArg {
    const int* starts;
    const int* counts;
    const unsigned short* srt;
    const float* adst;
    const float* asrc;
    const unsigned short* feats;
    const float* pw;
    int pwi;
    int hasLoop;
};

typedef __attribute__((ext_vector_type(8))) short short8;
typedef __attribute__((ext_vector_type(8))) unsigned short ushort8;
typedef __attribute__((ext_vector_type(4))) float floatx4;

__device__ __forceinline__ unsigned short f2bf(float x) {
    unsigned b = __float_as_uint(x);
    b = b + 0x7fffu + ((b >> 16) & 1u);   // RNE
    return (unsigned short)(b >> 16);
}

__device__ __forceinline__ float4 leakyexp4(float4 ad, float4 as) {
    float v0 = ad.x + as.x, v1 = ad.y + as.y, v2 = ad.z + as.z, v3 = ad.w + as.w;
    v0 = v0 > 0.f ? v0 : NEG * v0;
    v1 = v1 > 0.f ? v1 : NEG * v1;
    v2 = v2 > 0.f ? v2 : NEG * v2;
    v3 = v3 > 0.f ? v3 : NEG * v3;
    return make_float4(__expf(v0), __expf(v1), __expf(v2), __expf(v3));
}

// ---------------- transpose embedding weights ----------------
__global__ void transpose_emb(const float* __restrict__ wev, const float* __restrict__ wec,
                              float* __restrict__ out)
{
    int i = blockIdx.x * 256 + threadIdx.x;
    if (i < 8192) { out[i] = wev[(i & 127) * 64 + (i >> 7)]; return; }
    if (i < 16384) { int j = i - 8192; out[i] = wec[(j & 127) * 64 + (j >> 7)]; }
}

// ---------------- M[p] = W_p^T @ [attL | attR]  (128x8 per projection) ----------------
__global__ void make_M(MArgs a, float* __restrict__ Mbuf)
{
    int b = blockIdx.x;
    const float* W  = a.w[b];
    const float* AL = a.al[b];
    const float* AR = a.ar[b];
    for (int e = threadIdx.x; e < 1024; e += 256) {
        int k = e >> 3, h = e & 7;
        const float* att = (h < 4) ? AL : AR;
        int hh = h & 3;
        float s = 0.f;
        for (int c = 0; c < 128; c++) s += W[c * 128 + k] * att[c * 4 + hh];
        Mbuf[b * 1024 + e] = s;
    }
}

// ---------------- pre-convert all 8 W matrices to bf16 in MFMA-fragment order ----
// Wbf[w][((ct*4+kc)*64 + lane)*8 + j] = bf16(W_w[(ct*16 + (lane&15))*128 + kc*32 + (lane>>4)*8 + j])
// so a B-fragment load in the proj kernel is a single coalesced 16B/lane read.
__global__ void prep_W(MArgs a, unsigned short* __restrict__ Wbf)
{
    int tid = blockIdx.x * 256 + threadIdx.x;   // 0..16383
    int w = tid >> 11;
    int idx = tid & 2047;
    int tile = idx >> 6;          // ct*4 + kc
    int lane = idx & 63;
    int ct = tile >> 2, kc = tile & 3;
    int n = ct * 16 + (lane & 15);
    int k0 = kc * 32 + (lane >> 4) * 8;
    const float* src = a.w[w] + n * 128 + k0;
    short8 v;
#pragma unroll
    for (int j = 0; j < 8; j++) v[j] = (short)f2bf(src[j]);
    *(short8*)&Wbf[(size_t)tid * 8] = v;
}

// ---------------- embedding GEMM + LayerNorm ----------------
__global__ void embed_ln(const float* __restrict__ x, const float* __restrict__ Wt,
                         const float* __restrict__ g, const float* __restrict__ b,
                         const float* __restrict__ pw, const float* __restrict__ sb,
                         float* __restrict__ F, float* __restrict__ C)
{
    __shared__ float lx[8][64];
    __shared__ float red[2][8][2];
    int c = threadIdx.x;
    int n0 = blockIdx.x * 8;
    for (int t = c; t < 8 * 64; t += 128) {
        lx[t >> 6][t & 63] = x[(size_t)(n0 + (t >> 6)) * 64 + (t & 63)];
    }
    __syncthreads();
    float acc[8];
#pragma unroll
    for (int m = 0; m < 8; m++) acc[m] = 0.f;
    for (int k = 0; k < 64; k++) {
        float w = Wt[k * 128 + c];
#pragma unroll
        for (int m = 0; m < 8; m++) acc[m] += lx[m][k] * w;
    }
    int lane = c & 63, wv = c >> 6;
#pragma unroll
    for (int m = 0; m < 8; m++) {
        float s1 = acc[m], s2 = acc[m] * acc[m];
        for (int off = 32; off; off >>= 1) { s1 += __shfl_xor(s1, off); s2 += __shfl_xor(s2, off); }
        if (lane == 0) { red[wv][m][0] = s1; red[wv][m][1] = s2; }
    }
    __syncthreads();
    float biassum = pw[0] * sb[c] + pw[1] * sb[128 + c];
    float gg = g[c], bb = b[c];
#pragma unroll
    for (int m = 0; m < 8; m++) {
        float s1 = red[0][m][0] + red[1][m][0];
        float s2 = red[0][m][1] + red[1][m][1];
        float mu  = s1 * (1.f / 128.f);
        float var = s2 * (1.f / 128.f) - mu * mu;
        float inv = rsqrtf(var + 1e-5f);
        float v = acc[m];
        size_t idx = (size_t)(n0 + m) * 128 + c;
        F[idx] = v + biassum;
        C[idx] = (v - mu) * inv * gg + bb;
    }
}

// ---------------- fused pair projection, wave-per-(rowgroup x colhalf) ----------------
// 256 threads = 4 waves: rg = w&1 picks 16 rows, chh = w>>1 picks 64 output cols
// AND which M matrix this wave projects. B-fragments are read directly from the
// pre-swizzled bf16 Wbf in global (L1/L2-resident, perfectly coalesced): no W
// staging, no stage barriers, LDS = 8 KB. 32 rows/block -> 1563 blocks, 6252
// waves (~24/CU) vs old 3125 (~12/CU).
__global__ __launch_bounds__(256) void mfma_proj2(
    const float* __restrict__ in,        // [NN][128] fp32
    const unsigned short* __restrict__ Wp0, const unsigned short* __restrict__ Wp1,
    const float* __restrict__ M0, const float* __restrict__ M1,
    unsigned short* __restrict__ ob0, unsigned short* __restrict__ ob1,
    float4* __restrict__ dl0, float4* __restrict__ dr0,
    float4* __restrict__ dl1, float4* __restrict__ dr1)
{
    __shared__ float ML[2048];            // 2 x 128 x 8

    int t = threadIdx.x;
    for (int i = t; i < 2048; i += 256) ML[i] = (i < 1024) ? M0[i] : M1[i - 1024];
    __syncthreads();

    int w = t >> 6, lane = t & 63;
    int rg = w & 1, chh = w >> 1;
    int ln = lane & 15, quad = lane >> 4;
    int rbase = blockIdx.x * 32 + rg * 16;
    int row = rbase + ln;
    int arow = (row < NN) ? row : (NN - 1);
    const float* MLh = &ML[chh * 1024];

    short8 afrag[4];
    float p[8];
#pragma unroll
    for (int h = 0; h < 8; h++) p[h] = 0.f;
#pragma unroll
    for (int kc = 0; kc < 4; kc++) {
        int k0 = kc * 32 + quad * 8;
        const float* ap = in + (size_t)arow * 128 + k0;
        float av[8];
#pragma unroll
        for (int j = 0; j < 8; j++) av[j] = ap[j];
#pragma unroll
        for (int j = 0; j < 8; j++) {
            afrag[kc][j] = (short)f2bf(av[j]);
            const float* mrow = &MLh[(k0 + j) * 8];
#pragma unroll
            for (int h = 0; h < 8; h++) p[h] += av[j] * mrow[h];
        }
    }
#pragma unroll
    for (int h = 0; h < 8; h++) {
        p[h] += __shfl_xor(p[h], 16);
        p[h] += __shfl_xor(p[h], 32);
    }
    if (quad == 0 && row < NN) {
        if (chh == 0) {
            dl0[row] = make_float4(p[0], p[1], p[2], p[3]);
            dr0[row] = make_float4(p[4], p[5], p[6], p[7]);
        } else {
            dl1[row] = make_float4(p[0], p[1], p[2], p[3]);
            dr1[row] = make_float4(p[4], p[5], p[6], p[7]);
        }
    }

    // ---- phase 0: MFMA with Wp0 (this wave's 4 ct tiles) ----
#pragma unroll
    for (int cti = 0; cti < 4; cti++) {
        int ct = chh * 4 + cti;
        floatx4 acc = {0.f, 0.f, 0.f, 0.f};
#pragma unroll
        for (int kc = 0; kc < 4; kc++) {
            short8 bfr = *(const short8*)&Wp0[(size_t)((ct * 4 + kc) * 64 + lane) * 8];
            acc = __builtin_amdgcn_mfma_f32_16x16x32_bf16(afrag[kc], bfr, acc, 0, 0, 0);
        }
#pragma unroll
        for (int r = 0; r < 4; r++) {
            int rr = rbase + quad * 4 + r;
            if (rr < NN) ob0[(size_t)rr * 128 + ct * 16 + ln] = f2bf(acc[r]);
        }
    }
    // ---- phase 1: MFMA with Wp1 ----
#pragma unroll
    for (int cti = 0; cti < 4; cti++) {
        int ct = chh * 4 + cti;
        floatx4 acc = {0.f, 0.f, 0.f, 0.f};
#pragma unroll
        for (int kc = 0; kc < 4; kc++) {
            short8 bfr = *(const short8*)&Wp1[(size_t)((ct * 4 + kc) * 64 + lane) * 8];
            acc = __builtin_amdgcn_mfma_f32_16x16x32_bf16(afrag[kc], bfr, acc, 0, 0, 0);
        }
#pragma unroll
        for (int r = 0; r < 4; r++) {
            int rr = rbase + quad * 4 + r;
            if (rr < NN) ob1[(size_t)rr * 128 + ct * 16 + ln] = f2bf(acc[r]);
        }
    }
}

// ================= two-level bucket sort (8 edge lists) =================
__global__ void zero_bcnt(int* __restrict__ p)
{
    int i = blockIdx.x * 256 + threadIdx.x;
    if (i < 8 * NBKT) p[i] = 0;
}

__global__ void bucket_count(Ptr8 dst, int* __restrict__ bcnt)
{
    __shared__ int h[NBKT];
    int l = blockIdx.x / PA_B, cb = blockIdx.x % PA_B;
    const int* dp = dst.p[l];
    for (int i = threadIdx.x; i < NBKT; i += 256) h[i] = 0;
    __syncthreads();
    int e0 = cb * CHUNKA;
    for (int i = threadIdx.x; i < CHUNKA; i += 256) {
        int e = e0 + i;
        if (e < EE) atomicAdd(&h[dp[e] >> BSH], 1);
    }
    __syncthreads();
    for (int i = threadIdx.x; i < NBKT; i += 256)
        if (h[i]) atomicAdd(&bcnt[l * NBKT + i], h[i]);
}

__global__ void bucket_scan(const int* __restrict__ bcnt, int* __restrict__ bstart,
                            int* __restrict__ bcur)
{
    __shared__ int sh[NBKT];
    int l = blockIdx.x;
    for (int i = threadIdx.x; i < NBKT; i += 256) sh[i] = bcnt[l * NBKT + i];
    __syncthreads();
    if (threadIdx.x == 0) {
        int acc = 0;
        for (int i = 0; i < NBKT; i++) { int t = sh[i]; sh[i] = acc; acc += t; }
    }
    __syncthreads();
    for (int i = threadIdx.x; i < NBKT; i += 256) {
        bstart[l * (NBKT + 1) + i] = sh[i];
        bcur[l * NBKT + i] = sh[i];
    }
    if (threadIdx.x == 0) bstart[l * (NBKT + 1) + NBKT] = EE;
}

__global__ void bucket_place(Ptr8 src, Ptr8 dst, int* __restrict__ bcur,
                             unsigned* __restrict__ recs)
{
    __shared__ int h[NBKT];
    __shared__ int base[NBKT];
    int l = blockIdx.x / PA_B, cb = blockIdx.x % PA_B;
    const int* sp = src.p[l];
    const int* dp = dst.p[l];
    for (int i = threadIdx.x; i < NBKT; i += 256) h[i] = 0;
    __syncthreads();
    int e0 = cb * CHUNKA;
    for (int i = threadIdx.x; i < CHUNKA; i += 256) {
        int e = e0 + i;
        if (e < EE) atomicAdd(&h[dp[e] >> BSH], 1);
    }
    __syncthreads();
    for (int i = threadIdx.x; i < NBKT; i += 256) {
        int c = h[i];
        base[i] = c ? atomicAdd(&bcur[l * NBKT + i], c) : 0;
        h[i] = 0;
    }
    __syncthreads();
    unsigned* rl = recs + (size_t)l * EE;
    for (int i = threadIdx.x; i < CHUNKA; i += 256) {
        int e = e0 + i;
        if (e >= EE) continue;
        int d = dp[e];
        int b = d >> BSH;
        int pos = base[b] + atomicAdd(&h[b], 1);
        rl[pos] = ((unsigned)sp[e] << 16) | (unsigned)d;
    }
}

// one block per 512-dst bucket: stage recs in LDS, parallel scan, exact placement
__global__ __launch_bounds__(256) void bucket_final(
    const unsigned* __restrict__ recs, const int* __restrict__ bstart,
    int* __restrict__ starts8, int* __restrict__ counts8,
    unsigned short* __restrict__ sortedU)
{
    __shared__ unsigned R[FCAP];
    __shared__ int cnt[512];
    __shared__ int cur[512];
    __shared__ int psum[256];
    int l = blockIdx.x / NBKT, b = blockIdx.x % NBKT;
    int d0 = b << BSH;
    int nd = min(512, NN - d0);
    int ebase = bstart[l * (NBKT + 1) + b];
    int ecnt  = bstart[l * (NBKT + 1) + b + 1] - ebase;
    const unsigned* rp = recs + (size_t)l * EE + ebase;
    int t = threadIdx.x;
    bool inLds = (ecnt <= FCAP);

    for (int i = t; i < 512; i += 256) cnt[i] = 0;
    __syncthreads();
    for (int i = t; i < ecnt; i += 256) {
        unsigned r = rp[i];
        if (inLds) R[i] = r;
        atomicAdd(&cnt[(r & 0xffffu) - d0], 1);
    }
    __syncthreads();
    // exclusive scan of cnt[512]: pairwise partials + 256-ladder
    int s0 = cnt[2 * t] + cnt[2 * t + 1];
    psum[t] = s0;
    __syncthreads();
    for (int off = 1; off < 256; off <<= 1) {
        int x = (t >= off) ? psum[t - off] : 0;
        __syncthreads();
        psum[t] += x;
        __syncthreads();
    }
    int excl = psum[t] - s0;
    cur[2 * t] = excl;
    cur[2 * t + 1] = excl + cnt[2 * t];
    __syncthreads();
    for (int i = t; i < nd; i += 256) {
        starts8[l * NN + d0 + i] = ebase + cur[i];
        counts8[l * NN + d0 + i] = cnt[i];
    }
    __syncthreads();
    unsigned short* so = sortedU + (size_t)l * EE + ebase;
    for (int i = t; i < ecnt; i += 256) {
        unsigned r = inLds ? R[i] : rp[i];
        int dloc = (int)(r & 0xffffu) - d0;
        int pos = atomicAdd(&cur[dloc], 1);
        so[pos] = (unsigned short)(r >> 16);
    }
}

// ---------------- fused pair aggregation, 16-lane groups, register-held exp ----
// 256 threads = 16 groups of 16 lanes; group = one (dst, segment) pair.
// Pass 1 is statically unrolled to 4 masked iterations (CAP=64 = 4*16); the
// exp values stay in named registers e0..e3 (no scratch), so pass 2 computes
// the normalized weights WITHOUT re-reading asrc or re-computing exp --
// removes a ~500-cycle global round-trip from the critical path. Weights and
// src ids are packed {bits(w), s} in LDS; the gather reads a pair per
// ds_read_b128. No __syncthreads anywhere.
__global__ __launch_bounds__(256, 6) void agg_fused(
    SegArg A, SegArg B,
    const float* __restrict__ bias0, const float* __restrict__ bias1,
    float* __restrict__ acc, int mode)
{
    __shared__ uint2 pSh[16][CAP];   // 8 KB: packed {weight bits, src id}

    int t = threadIdx.x;
    int gid = t >> 4;            // 0..15: group (dst-local * 2 + seg)
    int sub = t & 15;
    int seg = gid & 1;
    int d   = blockIdx.x * 8 + (gid >> 1);

    const int* starts = seg ? B.starts : A.starts;
    const int* counts = seg ? B.counts : A.counts;
    const unsigned short* srt = seg ? B.srt : A.srt;
    const float* adst = seg ? B.adst : A.adst;
    const float* asrc = seg ? B.asrc : A.asrc;
    const unsigned short* feats = seg ? B.feats : A.feats;
    const float* pw = seg ? B.pw : A.pw;
    int pwi = seg ? B.pwi : A.pwi;
    int hasLoop = seg ? B.hasLoop : A.hasLoop;

    int base = starts[d];
    int k = counts[d];
    int kTot = k + hasLoop;

    float4 ad = *(const float4*)(adst + (size_t)d * 4);

    // pass 1: denominators, exp held in registers (static names, no scratch)
    float den0 = 0.f, den1 = 0.f, den2 = 0.f, den3 = 0.f;
    float4 e0 = {0,0,0,0}, e1 = {0,0,0,0}, e2 = {0,0,0,0}, e3 = {0,0,0,0};
    int s0 = 0, s1 = 0, s2 = 0, s3 = 0;
    int ia = sub, ib = sub + 16, ic = sub + 32, id = sub + 48;
    if (ia < kTot) {
        s0 = (ia < k) ? (int)srt[base + ia] : d;
        e0 = leakyexp4(ad, *(const float4*)(asrc + (size_t)s0 * 4));
        den0 += e0.x; den1 += e0.y; den2 += e0.z; den3 += e0.w;
    }
    if (ib < kTot) {
        s1 = (ib < k) ? (int)srt[base + ib] : d;
        e1 = leakyexp4(ad, *(const float4*)(asrc + (size_t)s1 * 4));
        den0 += e1.x; den1 += e1.y; den2 += e1.z; den3 += e1.w;
    }
    if (ic < kTot) {
        s2 = (ic < k) ? (int)srt[base + ic] : d;
        e2 = leakyexp4(ad, *(const float4*)(asrc + (size_t)s2 * 4));
        den0 += e2.x; den1 += e2.y; den2 += e2.z; den3 += e2.w;
    }
    if (id < kTot) {
        s3 = (id < k) ? (int)srt[base + id] : d;
        e3 = leakyexp4(ad, *(const float4*)(asrc + (size_t)s3 * 4));
        den0 += e3.x; den1 += e3.y; den2 += e3.z; den3 += e3.w;
    }
    for (int i = sub + 64; i < kTot; i += 16) {   // essentially never
        int s = (i < k) ? (int)srt[base + i] : d;
        float4 e = leakyexp4(ad, *(const float4*)(asrc + (size_t)s * 4));
        den0 += e.x; den1 += e.y; den2 += e.z; den3 += e.w;
    }
#pragma unroll
    for (int off = 1; off <= 8; off <<= 1) {
        den0 += __shfl_xor(den0, off); den1 += __shfl_xor(den1, off);
        den2 += __shfl_xor(den2, off); den3 += __shfl_xor(den3, off);
    }
    float scale = 0.25f * (pw ? pw[pwi] : 1.0f);
    float r0 = scale / (den0 + 1e-16f);
    float r1 = scale / (den1 + 1e-16f);
    float r2 = scale / (den2 + 1e-16f);
    float r3 = scale / (den3 + 1e-16f);

    // pass 2: weights straight from registers -> packed LDS
    if (ia < kTot) pSh[gid][ia] = make_uint2(
        __float_as_uint(e0.x * r0 + e0.y * r1 + e0.z * r2 + e0.w * r3), (unsigned)s0);
    if (ib < kTot) pSh[gid][ib] = make_uint2(
        __float_as_uint(e1.x * r0 + e1.y * r1 + e1.z * r2 + e1.w * r3), (unsigned)s1);
    if (ic < kTot) pSh[gid][ic] = make_uint2(
        __float_as_uint(e2.x * r0 + e2.y * r1 + e2.z * r2 + e2.w * r3), (unsigned)s2);
    if (id < kTot) pSh[gid][id] = make_uint2(
        __float_as_uint(e3.x * r0 + e3.y * r1 + e3.z * r2 + e3.w * r3), (unsigned)s3);
    // producer/consumer in the same wave: in-order LDS pipeline, no barrier

    // gather: lane owns channels sub*8 .. sub*8+7; pair-unrolled
    float a[8];
#pragma unroll
    for (int i = 0; i < 8; i++) a[i] = 0.f;
    const unsigned short* fbase = feats + sub * 8;
    int kW = kTot < CAP ? kTot : CAP;
    int j = 0;
    for (; j + 2 <= kW; j += 2) {
        uint4 pq = *(const uint4*)&pSh[gid][j];      // {wA, sA, wB, sB}
        ushort8 va = *(const ushort8*)(fbase + (size_t)pq.y * 128);
        ushort8 vb = *(const ushort8*)(fbase + (size_t)pq.w * 128);
        float wa = __uint_as_float(pq.x), wb = __uint_as_float(pq.z);
#pragma unroll
        for (int i = 0; i < 8; i++) {
            a[i] += wa * __uint_as_float((unsigned)(unsigned short)va[i] << 16);
            a[i] += wb * __uint_as_float((unsigned)(unsigned short)vb[i] << 16);
        }
    }
    if (j < kW) {
        uint2 ps = pSh[gid][j];
        ushort8 v = *(const ushort8*)(fbase + (size_t)ps.y * 128);
        float wgt = __uint_as_float(ps.x);
#pragma unroll
        for (int i = 0; i < 8; i++)
            a[i] += wgt * __uint_as_float((unsigned)(unsigned short)v[i] << 16);
    }
    for (int jj = CAP; jj < kTot; ++jj) {     // essentially-never fallback
        int s = (jj < k) ? (int)srt[base + jj] : d;
        float4 e = leakyexp4(ad, *(const float4*)(asrc + (size_t)s * 4));
        float wgt = e.x * r0 + e.y * r1 + e.z * r2 + e.w * r3;
        ushort8 v = *(const ushort8*)(fbase + (size_t)s * 128);
#pragma unroll
        for (int i = 0; i < 8; i++)
            a[i] += wgt * __uint_as_float((unsigned)(unsigned short)v[i] << 16);
    }

    // combine the two segments of this dst (groups g <-> g^1, lanes xor 16)
#pragma unroll
    for (int i = 0; i < 8; i++) a[i] += __shfl_xor(a[i], 16);

    if (seg == 0) {
        size_t idx = (size_t)d * 128 + sub * 8;
        float4* ap = (float4*)(acc + idx);
        float4 lo = make_float4(a[0], a[1], a[2], a[3]);
        float4 hi = make_float4(a[4], a[5], a[6], a[7]);
        if (mode) {
            const float4* b0 = (const float4*)(bias0 + sub * 8);
            const float4* b1 = (const float4*)(bias1 + sub * 8);
            float4 c0 = b0[0], c1 = b0[1], d0v = b1[0], d1v = b1[1];
            ap[0] = make_float4(c0.x + d0v.x + lo.x, c0.y + d0v.y + lo.y,
                                c0.z + d0v.z + lo.z, c0.w + d0v.w + lo.w);
            ap[1] = make_float4(c1.x + d1v.x + hi.x, c1.y + d1v.y + hi.y,
                                c1.z + d1v.z + hi.z, c1.w + d1v.w + hi.w);
        } else {
            float4 rr0 = ap[0], rr1 = ap[1];
            ap[0] = make_float4(rr0.x + lo.x, rr0.y + lo.y, rr0.z + lo.z, rr0.w + lo.w);
            ap[1] = make_float4(rr1.x + hi.x, rr1.y + hi.y, rr1.z + hi.z, rr1.w + hi.w);
        }
    }
}

extern "C" void kernel_launch(void* const* d_in, const int* in_sizes, int n_in,
                              void* d_out, int out_size, void* d_ws, size_t ws_size,
                              hipStream_t stream)
{
    const float* x_var   = (const float*)d_in[0];
    const float* x_cls   = (const float*)d_in[1];
    const int*   mp_var  = (const int*)d_in[2];
    const int*   mp_cls  = (const int*)d_in[3];
    const int*   adj_pos = (const int*)d_in[4];
    const int*   adj_neg = (const int*)d_in[5];
    const float* W_var_emb = (const float*)d_in[6];
    const float* W_cls_emb = (const float*)d_in[7];
    const float* ln_var_g = (const float*)d_in[8];
    const float* ln_var_b = (const float*)d_in[9];
    const float* ln_cls_g = (const float*)d_in[10];
    const float* ln_cls_b = (const float*)d_in[11];
    const float* var_pw = (const float*)d_in[12];
    const float* cls_pw = (const float*)d_in[13];
    const float* sv_W  = (const float*)d_in[14];
    const float* sv_al = (const float*)d_in[15];
    const float* sv_ar = (const float*)d_in[16];
    const float* sv_b  = (const float*)d_in[17];
    const float* sc_W  = (const float*)d_in[18];
    const float* sc_al = (const float*)d_in[19];
    const float* sc_ar = (const float*)d_in[20];
    const float* sc_b  = (const float*)d_in[21];
    const float* cp_Wl = (const float*)d_in[22];
    const float* cp_Wr = (const float*)d_in[23];
    const float* cp_al = (const float*)d_in[24];
    const float* cp_ar = (const float*)d_in[25];
    const float* cp_b  = (const float*)d_in[26];
    const float* cn_Wl = (const float*)d_in[27];
    const float* cn_Wr = (const float*)d_in[28];
    const float* cn_al = (const float*)d_in[29];
    const float* cn_ar = (const float*)d_in[30];
    const float* cn_b  = (const float*)d_in[31];

    float* out0 = (float*)d_out;
    float* out1 = out0 + (size_t)NN * 128;

    float* ws = (float*)d_ws;
    size_t off = 0;
    auto alloc = [&](size_t n) { float* p = ws + off; off += n; return p; };
    float* Wt   = alloc(16384);
    float* Mbuf = alloc(8 * 1024);
    unsigned short* Wbf = (unsigned short*)alloc(8 * 8192);  // 8 x 32KB bf16, fragment order
    float* F   = alloc((size_t)NN * 128);
    float* G   = alloc((size_t)NN * 128);
    float* C   = alloc((size_t)NN * 128);   // hv; reused as 2x bf16 feats after self-proj
    float* D   = alloc((size_t)NN * 128);   // hc
    unsigned short* B1 = (unsigned short*)alloc((size_t)NN * 64);  // bf16 [NN][128]
    unsigned short* B2 = (unsigned short*)alloc((size_t)NN * 64);
    float* dl   = alloc(NN * 4);
    float* dr   = alloc(NN * 4);
    float* dl2  = alloc(NN * 4);
    float* dr2  = alloc(NN * 4);
    float* dl3  = alloc(NN * 4);
    float* dr3  = alloc(NN * 4);
    float* dl4  = alloc(NN * 4);
    float* dr4  = alloc(NN * 4);
    int* counts8 = (int*)alloc(8 * NN);
    int* starts8 = (int*)alloc(8 * NN);
    int* bcnt    = (int*)alloc(8 * NBKT);
    int* bstart  = (int*)alloc(8 * (NBKT + 1));
    int* bcur    = (int*)alloc(8 * NBKT);
    unsigned* recs = (unsigned*)alloc((size_t)8 * EE);
    unsigned short* sortedU = (unsigned short*)alloc((size_t)4 * EE);

    // carve two bf16 feats buffers out of C (dead after self projections)
    unsigned short* Pc = (unsigned short*)C;                       // [NN][128] bf16
    unsigned short* Pd = (unsigned short*)C + (size_t)NN * 128;    // [NN][128] bf16

    const float* WtEv = Wt;
    const float* WtEc = Wt + 8192;

    Ptr8 srcP, dstP;
    srcP.p[0] = mp_var;            dstP.p[0] = mp_var + EE;
    srcP.p[1] = mp_var + 2 * EE;   dstP.p[1] = mp_var + 3 * EE;
    srcP.p[2] = mp_cls;            dstP.p[2] = mp_cls + EE;
    srcP.p[3] = mp_cls + 2 * EE;   dstP.p[3] = mp_cls + 3 * EE;
    srcP.p[4] = adj_pos;           dstP.p[4] = adj_pos + EE;
    srcP.p[5] = adj_pos + EE;      dstP.p[5] = adj_pos;
    srcP.p[6] = adj_neg;           dstP.p[6] = adj_neg + EE;
    srcP.p[7] = adj_neg + EE;      dstP.p[7] = adj_neg;

    MArgs ma;
    ma.w[0] = sv_W;           ma.al[0] = sv_al;        ma.ar[0] = sv_ar;
    ma.w[1] = sv_W + 16384;   ma.al[1] = sv_al + 512;  ma.ar[1] = sv_ar + 512;
    ma.w[2] = sc_W;           ma.al[2] = sc_al;        ma.ar[2] = sc_ar;
    ma.w[3] = sc_W + 16384;   ma.al[3] = sc_al + 512;  ma.ar[3] = sc_ar + 512;
    ma.w[4] = cp_Wl;          ma.al[4] = cp_al;        ma.ar[4] = cp_ar;
    ma.w[5] = cp_Wr;          ma.al[5] = cp_al;        ma.ar[5] = cp_ar;
    ma.w[6] = cn_Wl;          ma.al[6] = cn_al;        ma.ar[6] = cn_ar;
    ma.w[7] = cn_Wr;          ma.al[7] = cn_al;        ma.ar[7] = cn_ar;

    // ---- two-level bucket sort of all 8 edge lists ----
    zero_bcnt<<<(8 * NBKT + 255) / 256, 256, 0, stream>>>(bcnt);
    bucket_count<<<8 * PA_B, 256, 0, stream>>>(dstP, bcnt);
    bucket_scan<<<8, 256, 0, stream>>>(bcnt, bstart, bcur);
    bucket_place<<<8 * PA_B, 256, 0, stream>>>(srcP, dstP, bcur, recs);
    bucket_final<<<8 * NBKT, 256, 0, stream>>>(recs, bstart, starts8, counts8, sortedU);

    transpose_emb<<<64, 256, 0, stream>>>(W_var_emb, W_cls_emb, Wt);
    make_M<<<8, 256, 0, stream>>>(ma, Mbuf);
    prep_W<<<64, 256, 0, stream>>>(ma, Wbf);
    embed_ln<<<NN / 8, 128, 0, stream>>>(x_var, WtEv, ln_var_g, ln_var_b, var_pw, sv_b, F, C);
    embed_ln<<<NN / 8, 128, 0, stream>>>(x_cls, WtEc, ln_cls_g, ln_cls_b, cls_pw, sc_b, G, D);

    const int PB = (NN + 31) / 32;   // 1563 blocks, 32 rows each
    const int AB = NN / 8;           // 6250 blocks, 8 dsts each

    // ---- self attention: fused pair projection + fused pair agg per side ----
    for (int side = 0; side < 2; ++side) {
        const float* h    = side ? D : C;
        float*       accp = side ? G : F;
        const float* pw   = side ? cls_pw : var_pw;
        int s0 = side * 2, s1 = side * 2 + 1;
        mfma_proj2<<<PB, 256, 0, stream>>>(h, Wbf + s0 * 16384, Wbf + s1 * 16384,
                                           Mbuf + s0 * 1024, Mbuf + s1 * 1024,
                                           B1, B2,
                                           (float4*)dl, (float4*)dr,
                                           (float4*)dl2, (float4*)dr2);
        SegArg SA, SB;
        SA.starts = starts8 + s0 * NN; SA.counts = counts8 + s0 * NN;
        SA.srt = sortedU + (size_t)s0 * EE;
        SA.adst = dl;  SA.asrc = dr;  SA.feats = B1; SA.pw = pw; SA.pwi = 0; SA.hasLoop = 1;
        SB.starts = starts8 + s1 * NN; SB.counts = counts8 + s1 * NN;
        SB.srt = sortedU + (size_t)s1 * EE;
        SB.adst = dl2; SB.asrc = dr2; SB.feats = B2; SB.pw = pw; SB.pwi = 1; SB.hasLoop = 1;
        agg_fused<<<AB, 256, 0, stream>>>(SA, SB, cp_b, cn_b, accp, 0);
    }

    // ---- cross attention: pair projections by shared input, fuse pos/neg agg ----
    mfma_proj2<<<PB, 256, 0, stream>>>(F, Wbf + 4 * 16384, Wbf + 6 * 16384,
                                       Mbuf + 4 * 1024, Mbuf + 6 * 1024,
                                       B1, Pc,
                                       (float4*)dl, (float4*)dr,     // pos: al, ar_
                                       (float4*)dl3, (float4*)dr3);  // neg: al, ar_
    mfma_proj2<<<PB, 256, 0, stream>>>(G, Wbf + 5 * 16384, Wbf + 7 * 16384,
                                       Mbuf + 5 * 1024, Mbuf + 7 * 1024,
                                       B2, Pd,
                                       (float4*)dl2, (float4*)dr2,   // pos: al_, ar
                                       (float4*)dl4, (float4*)dr4);  // neg: al_, ar

    {   // out0 (var nodes): seg4 (pos) + seg6 (neg), bias written in-kernel
        SegArg SA, SB;
        SA.starts = starts8 + 4 * NN; SA.counts = counts8 + 4 * NN;
        SA.srt = sortedU + (size_t)4 * EE;
        SA.adst = dl;  SA.asrc = dr2; SA.feats = B2; SA.pw = nullptr; SA.pwi = 0; SA.hasLoop = 0;
        SB.starts = starts8 + 6 * NN; SB.counts = counts8 + 6 * NN;
        SB.srt = sortedU + (size_t)6 * EE;
        SB.adst = dl3; SB.asrc = dr4; SB.feats = Pd; SB.pw = nullptr; SB.pwi = 0; SB.hasLoop = 0;
        agg_fused<<<AB, 256, 0, stream>>>(SA, SB, cp_b, cn_b, out0, 1);
    }
    {   // out1 (cls nodes): seg5 (pos) + seg7 (neg)
        SegArg SA, SB;
        SA.starts = starts8 + 5 * NN; SA.counts = counts8 + 5 * NN;
        SA.srt = sortedU + (size_t)5 * EE;
        SA.adst = dl2; SA.asrc = dr;  SA.feats = B1; SA.pw = nullptr; SA.pwi = 0; SA.hasLoop = 0;
        SB.starts = starts8 + 7 * NN; SB.counts = counts8 + 7 * NN;
        SB.srt = sortedU + (size_t)7 * EE;
        SB.adst = dl4; SB.asrc = dr3; SB.feats = Pc; SB.pw = nullptr; SB.pwi = 0; SB.hasLoop = 0;
        agg_fused<<<AB, 256, 0, stream>>>(SA, SB, cp_b, cn_b, out1, 1);
    }
}